// Round 1
// baseline (1100.816 us; speedup 1.0000x reference)
//
#include <hip/hip_runtime.h>
#include <hip/hip_bf16.h>

// ---------------------------------------------------------------------------
// GATv2 x2 + LN + ELU + residual, f32 baseline.
// Graph: N nodes, E edges + N self-loops appended (PyG add_self_loops).
// ---------------------------------------------------------------------------

#define HC1 512   // heads*channels layer 1 (4*128)
#define HC2 256   // layer 2 (1*256)
#define D_IN 256
#define ED 4

// ------------------------- f32 tiled GEMM ----------------------------------
// C[M,N] = A[M,K] @ B[K,N].  N % 64 == 0, K % 16 == 0. M guarded.
#define GTM 128
#define GTN 64
#define GTK 16

__global__ __launch_bounds__(256)
void gemm_f32_kernel(const float* __restrict__ A, const float* __restrict__ B,
                     float* __restrict__ C, int M, int K, int N) {
  __shared__ float As[GTK][GTM + 4];   // +4 pad: conflict-free transposed store
  __shared__ float Bs[GTK][GTN];
  const int t  = threadIdx.x;
  const int n0 = blockIdx.x * GTN;
  const int m0 = blockIdx.y * GTM;
  const int tx = t & 15, ty = t >> 4;
  const int r0 = ty * 8, c0 = tx * 4;

  float4 acc[8];
#pragma unroll
  for (int i = 0; i < 8; i++) acc[i] = make_float4(0.f, 0.f, 0.f, 0.f);

  for (int k0 = 0; k0 < K; k0 += GTK) {
#pragma unroll
    for (int i = 0; i < 8; i++) {           // A tile 128x16 (transposed store)
      int idx = i * 256 + t;
      int kk = idx & 15, r = idx >> 4;
      int row = m0 + r;
      As[kk][r] = (row < M) ? A[(size_t)row * K + k0 + kk] : 0.f;
    }
#pragma unroll
    for (int i = 0; i < 4; i++) {           // B tile 16x64
      int idx = i * 256 + t;
      int kk = idx >> 6, c = idx & 63;
      Bs[kk][c] = B[(size_t)(k0 + kk) * N + n0 + c];
    }
    __syncthreads();
#pragma unroll
    for (int kk = 0; kk < GTK; kk++) {
      const float4 b  = *(const float4*)&Bs[kk][c0];
      const float4 a0 = *(const float4*)&As[kk][r0];
      const float4 a1 = *(const float4*)&As[kk][r0 + 4];
      float ar[8] = {a0.x, a0.y, a0.z, a0.w, a1.x, a1.y, a1.z, a1.w};
#pragma unroll
      for (int i = 0; i < 8; i++) {
        acc[i].x = fmaf(ar[i], b.x, acc[i].x);
        acc[i].y = fmaf(ar[i], b.y, acc[i].y);
        acc[i].z = fmaf(ar[i], b.z, acc[i].z);
        acc[i].w = fmaf(ar[i], b.w, acc[i].w);
      }
    }
    __syncthreads();
  }
#pragma unroll
  for (int i = 0; i < 8; i++) {
    int row = m0 + r0 + i;
    if (row < M) *(float4*)&C[(size_t)row * N + n0 + c0] = acc[i];
  }
}

// ------------------------- edge-attr mean ----------------------------------
__global__ void mean_kernel(const float* __restrict__ eattr, float* __restrict__ sums, int E) {
  int tid = blockIdx.x * blockDim.x + threadIdx.x;
  int stride = gridDim.x * blockDim.x;
  float l0 = 0.f, l1 = 0.f, l2 = 0.f, l3 = 0.f;
  for (int e = tid; e < E; e += stride) {
    float4 v = ((const float4*)eattr)[e];
    l0 += v.x; l1 += v.y; l2 += v.z; l3 += v.w;
  }
#pragma unroll
  for (int o = 1; o < 64; o <<= 1) {
    l0 += __shfl_xor(l0, o); l1 += __shfl_xor(l1, o);
    l2 += __shfl_xor(l2, o); l3 += __shfl_xor(l3, o);
  }
  if ((threadIdx.x & 63) == 0) {
    atomicAdd(&sums[0], l0); atomicAdd(&sums[1], l1);
    atomicAdd(&sums[2], l2); atomicAdd(&sums[3], l3);
  }
}

// self-loop edge term: eloop1 = mean_ea @ We1 (512), eloop2 = mean_ea @ We2 (256)
__global__ void eloop_kernel(const float* __restrict__ sums,
                             const float* __restrict__ We1, const float* __restrict__ We2,
                             float* __restrict__ eloop1, float* __restrict__ eloop2, float invE) {
  float m0 = sums[0] * invE, m1 = sums[1] * invE, m2 = sums[2] * invE, m3 = sums[3] * invE;
  int t = threadIdx.x;  // 512
  eloop1[t] = m0 * We1[t] + m1 * We1[512 + t] + m2 * We1[1024 + t] + m3 * We1[1536 + t];
  if (t < 256)
    eloop2[t] = m0 * We2[t] + m1 * We2[256 + t] + m2 * We2[512 + t] + m3 * We2[768 + t];
}

// ------------------------- CSR build ---------------------------------------
__global__ void count_kernel(const int* __restrict__ ei, int* __restrict__ counts, int E, int Etot) {
  int tid = blockIdx.x * blockDim.x + threadIdx.x;
  int stride = gridDim.x * blockDim.x;
  for (int e = tid; e < Etot; e += stride) {
    int dst = (e < E) ? ei[E + e] : (e - E);
    atomicAdd(&counts[dst], 1);
  }
}

__global__ __launch_bounds__(1024)
void scan_kernel(const int* __restrict__ counts, int* __restrict__ offs, int N) {
  __shared__ int lds[1024];
  int tid = threadIdx.x;
  int carry = 0;
  if (tid == 0) offs[0] = 0;
  for (int base = 0; base < N; base += 1024) {
    int i = base + tid;
    int v = (i < N) ? counts[i] : 0;
    lds[tid] = v;
    __syncthreads();
    for (int o = 1; o < 1024; o <<= 1) {
      int add = (tid >= o) ? lds[tid - o] : 0;
      __syncthreads();
      lds[tid] += add;
      __syncthreads();
    }
    if (i < N) offs[i + 1] = carry + lds[tid];
    int tot = lds[1023];
    __syncthreads();
    carry += tot;
  }
}

__global__ void fill_kernel(const int* __restrict__ ei, const int* __restrict__ offs,
                            int* __restrict__ cursor, int* __restrict__ elist, int E, int Etot) {
  int tid = blockIdx.x * blockDim.x + threadIdx.x;
  int stride = gridDim.x * blockDim.x;
  for (int e = tid; e < Etot; e += stride) {
    int dst = (e < E) ? ei[E + e] : (e - E);
    int pos = atomicAdd(&cursor[dst], 1);
    elist[offs[dst] + pos] = e;
  }
}

// ------------------------- layer-1 edge scores (H=4, C=128) ----------------
// one wave per edge; lane covers 8 consecutive channels.
__global__ __launch_bounds__(256)
void edge1_kernel(const int* __restrict__ ei, const float* __restrict__ eattr,
                  const float* __restrict__ xl, const float* __restrict__ xr,
                  const float* __restrict__ We, const float* __restrict__ eloop,
                  const float* __restrict__ att, float* __restrict__ sc,
                  float* __restrict__ denom, int E, int Etot) {
  int e = blockIdx.x * 4 + (threadIdx.x >> 6);
  if (e >= Etot) return;
  int lane = threadIdx.x & 63;
  int src, dst;
  if (e < E) { src = ei[e]; dst = ei[E + e]; } else { src = e - E; dst = src; }
  int c0 = lane * 8;

  float4 a0 = *(const float4*)(xl + (size_t)src * HC1 + c0);
  float4 a1 = *(const float4*)(xl + (size_t)src * HC1 + c0 + 4);
  float4 b0 = *(const float4*)(xr + (size_t)dst * HC1 + c0);
  float4 b1 = *(const float4*)(xr + (size_t)dst * HC1 + c0 + 4);
  float xa[8] = {a0.x, a0.y, a0.z, a0.w, a1.x, a1.y, a1.z, a1.w};
  float xb[8] = {b0.x, b0.y, b0.z, b0.w, b1.x, b1.y, b1.z, b1.w};

  float et[8];
  if (e < E) {
    float ea0 = eattr[(size_t)e * 4 + 0], ea1 = eattr[(size_t)e * 4 + 1];
    float ea2 = eattr[(size_t)e * 4 + 2], ea3 = eattr[(size_t)e * 4 + 3];
    float4 p00 = *(const float4*)(We + 0 * 512 + c0), p01 = *(const float4*)(We + 0 * 512 + c0 + 4);
    float4 p10 = *(const float4*)(We + 1 * 512 + c0), p11 = *(const float4*)(We + 1 * 512 + c0 + 4);
    float4 p20 = *(const float4*)(We + 2 * 512 + c0), p21 = *(const float4*)(We + 2 * 512 + c0 + 4);
    float4 p30 = *(const float4*)(We + 3 * 512 + c0), p31 = *(const float4*)(We + 3 * 512 + c0 + 4);
    float w0[8] = {p00.x, p00.y, p00.z, p00.w, p01.x, p01.y, p01.z, p01.w};
    float w1[8] = {p10.x, p10.y, p10.z, p10.w, p11.x, p11.y, p11.z, p11.w};
    float w2[8] = {p20.x, p20.y, p20.z, p20.w, p21.x, p21.y, p21.z, p21.w};
    float w3[8] = {p30.x, p30.y, p30.z, p30.w, p31.x, p31.y, p31.z, p31.w};
#pragma unroll
    for (int j = 0; j < 8; j++)
      et[j] = ea0 * w0[j] + ea1 * w1[j] + ea2 * w2[j] + ea3 * w3[j];
  } else {
    float4 l0 = *(const float4*)(eloop + c0), l1 = *(const float4*)(eloop + c0 + 4);
    float el[8] = {l0.x, l0.y, l0.z, l0.w, l1.x, l1.y, l1.z, l1.w};
#pragma unroll
    for (int j = 0; j < 8; j++) et[j] = el[j];
  }

  float4 A0 = *(const float4*)(att + c0), A1 = *(const float4*)(att + c0 + 4);
  float aw[8] = {A0.x, A0.y, A0.z, A0.w, A1.x, A1.y, A1.z, A1.w};
  float p = 0.f;
#pragma unroll
  for (int j = 0; j < 8; j++) {
    float m = xa[j] + xb[j] + et[j];
    float lm = (m > 0.f) ? m : 0.2f * m;
    p = fmaf(lm, aw[j], p);
  }
#pragma unroll
  for (int o = 1; o < 16; o <<= 1) p += __shfl_xor(p, o);
  if ((lane & 15) == 0) {
    int h = lane >> 4;
    float ex = expf(p);            // no max-subtraction needed: |score| is O(5)
    sc[(size_t)e * 4 + h] = ex;
    atomicAdd(denom + (size_t)dst * 4 + h, ex);
  }
}

// ------------------------- layer-2 edge scores (H=1, C=256) ----------------
__global__ __launch_bounds__(256)
void edge2_kernel(const int* __restrict__ ei, const float* __restrict__ eattr,
                  const float* __restrict__ xl, const float* __restrict__ xr,
                  const float* __restrict__ We, const float* __restrict__ eloop,
                  const float* __restrict__ att, float* __restrict__ sc,
                  float* __restrict__ denom, int E, int Etot) {
  int e = blockIdx.x * 4 + (threadIdx.x >> 6);
  if (e >= Etot) return;
  int lane = threadIdx.x & 63;
  int src, dst;
  if (e < E) { src = ei[e]; dst = ei[E + e]; } else { src = e - E; dst = src; }
  int c0 = lane * 4;

  float4 a = *(const float4*)(xl + (size_t)src * HC2 + c0);
  float4 b = *(const float4*)(xr + (size_t)dst * HC2 + c0);
  float xa[4] = {a.x, a.y, a.z, a.w};
  float xb[4] = {b.x, b.y, b.z, b.w};

  float et[4];
  if (e < E) {
    float ea0 = eattr[(size_t)e * 4 + 0], ea1 = eattr[(size_t)e * 4 + 1];
    float ea2 = eattr[(size_t)e * 4 + 2], ea3 = eattr[(size_t)e * 4 + 3];
    float4 q0 = *(const float4*)(We + 0 * 256 + c0);
    float4 q1 = *(const float4*)(We + 1 * 256 + c0);
    float4 q2 = *(const float4*)(We + 2 * 256 + c0);
    float4 q3 = *(const float4*)(We + 3 * 256 + c0);
    float w0[4] = {q0.x, q0.y, q0.z, q0.w};
    float w1[4] = {q1.x, q1.y, q1.z, q1.w};
    float w2[4] = {q2.x, q2.y, q2.z, q2.w};
    float w3[4] = {q3.x, q3.y, q3.z, q3.w};
#pragma unroll
    for (int j = 0; j < 4; j++)
      et[j] = ea0 * w0[j] + ea1 * w1[j] + ea2 * w2[j] + ea3 * w3[j];
  } else {
    float4 l = *(const float4*)(eloop + c0);
    et[0] = l.x; et[1] = l.y; et[2] = l.z; et[3] = l.w;
  }

  float4 A = *(const float4*)(att + c0);
  float aw[4] = {A.x, A.y, A.z, A.w};
  float p = 0.f;
#pragma unroll
  for (int j = 0; j < 4; j++) {
    float m = xa[j] + xb[j] + et[j];
    float lm = (m > 0.f) ? m : 0.2f * m;
    p = fmaf(lm, aw[j], p);
  }
#pragma unroll
  for (int o = 1; o < 64; o <<= 1) p += __shfl_xor(p, o);
  if (lane == 0) {
    float ex = expf(p);
    sc[e] = ex;
    atomicAdd(denom + dst, ex);
  }
}

// ------------------------- layer-1 aggregate + bias + LN + ELU -------------
__global__ __launch_bounds__(512)
void agg1_kernel(const int* __restrict__ ei, const int* __restrict__ elist,
                 const int* __restrict__ offs, const float* __restrict__ xl,
                 const float* __restrict__ sc, const float* __restrict__ denom,
                 const float* __restrict__ bias, const float* __restrict__ g,
                 const float* __restrict__ be, float* __restrict__ h1, int E) {
  int v = blockIdx.x, t = threadIdx.x;
  int h = t >> 7;
  float rden = 1.f / (denom[(size_t)v * 4 + h] + 1e-16f);
  int beg = offs[v], end = offs[v + 1];
  float acc = 0.f;
  for (int i = beg; i < end; i++) {
    int eid = elist[i];
    int src = (eid < E) ? ei[eid] : (eid - E);
    acc = fmaf(sc[(size_t)eid * 4 + h], xl[(size_t)src * HC1 + t], acc);
  }
  float val = acc * rden + bias[t];

  __shared__ float2 red[8];
  float s1 = val, s2 = val * val;
#pragma unroll
  for (int o = 1; o < 64; o <<= 1) { s1 += __shfl_xor(s1, o); s2 += __shfl_xor(s2, o); }
  int wid = t >> 6, lane = t & 63;
  if (lane == 0) red[wid] = make_float2(s1, s2);
  __syncthreads();
  float ts1 = 0.f, ts2 = 0.f;
#pragma unroll
  for (int i = 0; i < 8; i++) { ts1 += red[i].x; ts2 += red[i].y; }
  float mu = ts1 * (1.f / HC1);
  float var = ts2 * (1.f / HC1) - mu * mu;
  float y = (val - mu) * rsqrtf(var + 1e-5f) * g[t] + be[t];
  h1[(size_t)v * HC1 + t] = (y > 0.f) ? y : expm1f(y);   // ELU
}

// ------------------------- layer-2 aggregate + bias + LN + residual --------
__global__ __launch_bounds__(256)
void agg2_kernel(const int* __restrict__ ei, const int* __restrict__ elist,
                 const int* __restrict__ offs, const float* __restrict__ xl,
                 const float* __restrict__ sc, const float* __restrict__ denom,
                 const float* __restrict__ bias, const float* __restrict__ g,
                 const float* __restrict__ be, const float* __restrict__ xin,
                 float* __restrict__ out, int E) {
  int v = blockIdx.x, t = threadIdx.x;
  float rden = 1.f / (denom[v] + 1e-16f);
  int beg = offs[v], end = offs[v + 1];
  float acc = 0.f;
  for (int i = beg; i < end; i++) {
    int eid = elist[i];
    int src = (eid < E) ? ei[eid] : (eid - E);
    acc = fmaf(sc[eid], xl[(size_t)src * HC2 + t], acc);
  }
  float val = acc * rden + bias[t];

  __shared__ float2 red[4];
  float s1 = val, s2 = val * val;
#pragma unroll
  for (int o = 1; o < 64; o <<= 1) { s1 += __shfl_xor(s1, o); s2 += __shfl_xor(s2, o); }
  int wid = t >> 6, lane = t & 63;
  if (lane == 0) red[wid] = make_float2(s1, s2);
  __syncthreads();
  float ts1 = red[0].x + red[1].x + red[2].x + red[3].x;
  float ts2 = red[0].y + red[1].y + red[2].y + red[3].y;
  float mu = ts1 * (1.f / HC2);
  float var = ts2 * (1.f / HC2) - mu * mu;
  float y = (val - mu) * rsqrtf(var + 1e-5f) * g[t] + be[t];
  out[(size_t)v * HC2 + t] = y + xin[(size_t)v * HC2 + t];
}

// ---------------------------------------------------------------------------
extern "C" void kernel_launch(void* const* d_in, const int* in_sizes, int n_in,
                              void* d_out, int out_size, void* d_ws, size_t ws_size,
                              hipStream_t stream) {
  const float* x     = (const float*)d_in[0];
  const int*   ei    = (const int*)d_in[1];
  const float* eattr = (const float*)d_in[2];
  const float* Wl1   = (const float*)d_in[3];
  const float* Wr1   = (const float*)d_in[4];
  const float* We1   = (const float*)d_in[5];
  const float* att1  = (const float*)d_in[6];
  const float* b1    = (const float*)d_in[7];
  const float* g1    = (const float*)d_in[8];
  const float* be1   = (const float*)d_in[9];
  const float* Wl2   = (const float*)d_in[10];
  const float* Wr2   = (const float*)d_in[11];
  const float* We2   = (const float*)d_in[12];
  const float* att2  = (const float*)d_in[13];
  const float* b2    = (const float*)d_in[14];
  const float* g2    = (const float*)d_in[15];
  const float* be2   = (const float*)d_in[16];

  const int N    = in_sizes[0] / D_IN;     // 10000
  const int E    = in_sizes[2] / ED;       // 320000
  const int Etot = E + N;                  // self-loops appended

  // workspace bump allocator (256B aligned slots)
  char* w = (char*)d_ws;
  auto alloc = [&](size_t bytes) -> void* {
    void* p = (void*)w;
    w += (bytes + 255) & ~(size_t)255;
    return p;
  };
  float* xl1    = (float*)alloc((size_t)N * HC1 * 4);
  float* xr1    = (float*)alloc((size_t)N * HC1 * 4);
  float* h1     = (float*)alloc((size_t)N * HC1 * 4);
  float* sc1    = (float*)alloc((size_t)Etot * 4 * 4);
  float* sc2    = (float*)alloc((size_t)Etot * 4);
  char*  accb   = w;                       // zeroed region start
  float* denom1 = (float*)alloc((size_t)N * 4 * 4);
  float* denom2 = (float*)alloc((size_t)N * 4);
  int*   counts = (int*)alloc((size_t)N * 4);
  int*   cursor = (int*)alloc((size_t)N * 4);
  float* sums   = (float*)alloc(64);
  size_t accbytes = (size_t)(w - accb);
  int*   offs   = (int*)alloc((size_t)(N + 1) * 4);
  int*   elist  = (int*)alloc((size_t)Etot * 4);
  float* eloop1 = (float*)alloc(512 * 4);
  float* eloop2 = (float*)alloc(256 * 4);
  float* xl2 = xl1;   // layer-2 transforms reuse layer-1 regions (dead by then)
  float* xr2 = xr1;

  hipMemsetAsync(accb, 0, accbytes, stream);

  mean_kernel<<<256, 256, 0, stream>>>(eattr, sums, E);
  eloop_kernel<<<1, 512, 0, stream>>>(sums, We1, We2, eloop1, eloop2, 1.f / (float)E);

  count_kernel<<<1024, 256, 0, stream>>>(ei, counts, E, Etot);
  scan_kernel<<<1, 1024, 0, stream>>>(counts, offs, N);
  fill_kernel<<<1024, 256, 0, stream>>>(ei, offs, cursor, elist, E, Etot);

  dim3 gg1(HC1 / GTN, (N + GTM - 1) / GTM);
  gemm_f32_kernel<<<gg1, 256, 0, stream>>>(x, Wl1, xl1, N, D_IN, HC1);
  gemm_f32_kernel<<<gg1, 256, 0, stream>>>(x, Wr1, xr1, N, D_IN, HC1);

  edge1_kernel<<<(Etot + 3) / 4, 256, 0, stream>>>(ei, eattr, xl1, xr1, We1, eloop1,
                                                   att1, sc1, denom1, E, Etot);
  agg1_kernel<<<N, 512, 0, stream>>>(ei, elist, offs, xl1, sc1, denom1, b1, g1, be1, h1, E);

  dim3 gg2(HC2 / GTN, (N + GTM - 1) / GTM);
  gemm_f32_kernel<<<gg2, 256, 0, stream>>>(h1, Wl2, xl2, N, HC1, HC2);
  gemm_f32_kernel<<<gg2, 256, 0, stream>>>(h1, Wr2, xr2, N, HC1, HC2);

  edge2_kernel<<<(Etot + 3) / 4, 256, 0, stream>>>(ei, eattr, xl2, xr2, We2, eloop2,
                                                   att2, sc2, denom2, E, Etot);
  agg2_kernel<<<N, 256, 0, stream>>>(ei, elist, offs, xl2, sc2, denom2, b2, g2, be2,
                                     x, (float*)d_out, E);
}

// Round 2
// 699.865 us; speedup vs baseline: 1.5729x; 1.5729x over previous
//
#include <hip/hip_runtime.h>
#include <hip/hip_bf16.h>

#define HC1 512   // layer-1 heads*channels (4*128)
#define HC2 256   // layer-2 (1*256)
#define D_IN 256

typedef __hip_bfloat16  bf16;
typedef __hip_bfloat162 bf162;

// ------------------------- f32 GEMM, templated output ----------------------
#define GTM 128
#define GTN 64
#define GTK 16

__device__ inline void store4(float* p, float4 v) { *(float4*)p = v; }
__device__ inline void store4(bf16* p, float4 v) {
  bf162 lo, hi;
  lo.x = __float2bfloat16(v.x); lo.y = __float2bfloat16(v.y);
  hi.x = __float2bfloat16(v.z); hi.y = __float2bfloat16(v.w);
  *(bf162*)p       = lo;
  *(bf162*)(p + 2) = hi;
}

template <typename OT>
__global__ __launch_bounds__(256)
void gemm_kernel(const float* __restrict__ A, const float* __restrict__ B,
                 OT* __restrict__ C, int M, int K, int N) {
  __shared__ float As[GTK][GTM + 4];
  __shared__ float Bs[GTK][GTN];
  const int t  = threadIdx.x;
  const int n0 = blockIdx.x * GTN;
  const int m0 = blockIdx.y * GTM;
  const int tx = t & 15, ty = t >> 4;
  const int r0 = ty * 8, c0 = tx * 4;

  float4 acc[8];
#pragma unroll
  for (int i = 0; i < 8; i++) acc[i] = make_float4(0.f, 0.f, 0.f, 0.f);

  for (int k0 = 0; k0 < K; k0 += GTK) {
#pragma unroll
    for (int i = 0; i < 8; i++) {
      int idx = i * 256 + t;
      int kk = idx & 15, r = idx >> 4;
      int row = m0 + r;
      As[kk][r] = (row < M) ? A[(size_t)row * K + k0 + kk] : 0.f;
    }
#pragma unroll
    for (int i = 0; i < 4; i++) {
      int idx = i * 256 + t;
      int kk = idx >> 6, c = idx & 63;
      Bs[kk][c] = B[(size_t)(k0 + kk) * N + n0 + c];
    }
    __syncthreads();
#pragma unroll
    for (int kk = 0; kk < GTK; kk++) {
      const float4 b  = *(const float4*)&Bs[kk][c0];
      const float4 a0 = *(const float4*)&As[kk][r0];
      const float4 a1 = *(const float4*)&As[kk][r0 + 4];
      float ar[8] = {a0.x, a0.y, a0.z, a0.w, a1.x, a1.y, a1.z, a1.w};
#pragma unroll
      for (int i = 0; i < 8; i++) {
        acc[i].x = fmaf(ar[i], b.x, acc[i].x);
        acc[i].y = fmaf(ar[i], b.y, acc[i].y);
        acc[i].z = fmaf(ar[i], b.z, acc[i].z);
        acc[i].w = fmaf(ar[i], b.w, acc[i].w);
      }
    }
    __syncthreads();
  }
#pragma unroll
  for (int i = 0; i < 8; i++) {
    int row = m0 + r0 + i;
    if (row < M) store4(&C[(size_t)row * N + n0 + c0], acc[i]);
  }
}

// ------------------------- edge-attr mean ----------------------------------
__global__ void mean_kernel(const float* __restrict__ eattr, float* __restrict__ sums, int E) {
  int tid = blockIdx.x * blockDim.x + threadIdx.x;
  int stride = gridDim.x * blockDim.x;
  float l0 = 0.f, l1 = 0.f, l2 = 0.f, l3 = 0.f;
  for (int e = tid; e < E; e += stride) {
    float4 v = ((const float4*)eattr)[e];
    l0 += v.x; l1 += v.y; l2 += v.z; l3 += v.w;
  }
#pragma unroll
  for (int o = 1; o < 64; o <<= 1) {
    l0 += __shfl_xor(l0, o); l1 += __shfl_xor(l1, o);
    l2 += __shfl_xor(l2, o); l3 += __shfl_xor(l3, o);
  }
  if ((threadIdx.x & 63) == 0) {
    atomicAdd(&sums[0], l0); atomicAdd(&sums[1], l1);
    atomicAdd(&sums[2], l2); atomicAdd(&sums[3], l3);
  }
}

__global__ void meanw_kernel(const float* __restrict__ sums, float* __restrict__ mean4, float invE) {
  int t = threadIdx.x;
  if (t < 4) mean4[t] = sums[t] * invE;
}

// ------------------------- CSR build ---------------------------------------
__global__ void count_kernel(const int* __restrict__ ei, int* __restrict__ counts, int E, int Etot) {
  int tid = blockIdx.x * blockDim.x + threadIdx.x;
  int stride = gridDim.x * blockDim.x;
  for (int e = tid; e < Etot; e += stride) {
    int dst = (e < E) ? ei[E + e] : (e - E);
    atomicAdd(&counts[dst], 1);
  }
}

__global__ __launch_bounds__(1024)
void scan_kernel(const int* __restrict__ counts, int* __restrict__ offs, int N) {
  __shared__ int wsum[16];
  int tid = threadIdx.x, wid = tid >> 6, lane = tid & 63;
  if (tid == 0) offs[0] = 0;
  int carry = 0;
  for (int base = 0; base < N; base += 1024) {
    int i = base + tid;
    int v = (i < N) ? counts[i] : 0;
    int s = v;
#pragma unroll
    for (int o = 1; o < 64; o <<= 1) {
      int u = __shfl_up(s, o);
      if (lane >= o) s += u;
    }
    if (lane == 63) wsum[wid] = s;
    __syncthreads();
    if (wid == 0) {
      int t2 = (lane < 16) ? wsum[lane] : 0;
#pragma unroll
      for (int o = 1; o < 16; o <<= 1) {
        int u = __shfl_up(t2, o);
        if (lane >= o) t2 += u;
      }
      if (lane < 16) wsum[lane] = t2;
    }
    __syncthreads();
    int pre = (wid > 0) ? wsum[wid - 1] : 0;
    int tot = wsum[15];
    if (i < N) offs[i + 1] = carry + pre + s;
    carry += tot;
    __syncthreads();
  }
}

// fill CSR: store src index + edge attr (self-loops use mean_ea -> uniform path)
__global__ void fill_kernel(const int* __restrict__ ei, const int* __restrict__ offs,
                            int* __restrict__ cursor, const float* __restrict__ eattr,
                            const float* __restrict__ mean4, int* __restrict__ srcs,
                            float4* __restrict__ eaC, int E, int Etot) {
  int tid = blockIdx.x * blockDim.x + threadIdx.x;
  int stride = gridDim.x * blockDim.x;
  for (int e = tid; e < Etot; e += stride) {
    int src, dst;
    if (e < E) { src = ei[e]; dst = ei[E + e]; } else { src = e - E; dst = src; }
    int pos = atomicAdd(&cursor[dst], 1);
    int slot = offs[dst] + pos;
    srcs[slot] = src;
    eaC[slot] = (e < E) ? ((const float4*)eattr)[e] : *(const float4*)mean4;
  }
}

// ---------------- layer 1 fused: scores + softmax-agg + bias + LN + ELU ----
// one block (256 thr) per node; wave = head; lane covers 2 channels.
__global__ __launch_bounds__(256)
void fused1_kernel(const int* __restrict__ srcs, const float4* __restrict__ eaC,
                   const int* __restrict__ offs,
                   const bf16* __restrict__ xl, const bf16* __restrict__ xr,
                   const float* __restrict__ We, const float* __restrict__ att,
                   const float* __restrict__ bias, const float* __restrict__ g,
                   const float* __restrict__ be, float* __restrict__ h1) {
  const int v = blockIdx.x;
  const int t = threadIdx.x;
  const int wave = t >> 6, lane = t & 63;
  const int ch = wave * 128 + lane * 2;

  const float w0a = We[0 * HC1 + ch], w0b = We[0 * HC1 + ch + 1];
  const float w1a = We[1 * HC1 + ch], w1b = We[1 * HC1 + ch + 1];
  const float w2a = We[2 * HC1 + ch], w2b = We[2 * HC1 + ch + 1];
  const float w3a = We[3 * HC1 + ch], w3b = We[3 * HC1 + ch + 1];
  const float ata = att[ch], atb = att[ch + 1];
  bf162 xrv = *(const bf162*)(xr + (size_t)v * HC1 + ch);
  const float xra = __bfloat162float(xrv.x), xrb = __bfloat162float(xrv.y);

  const int beg = offs[v], end = offs[v + 1];
  float den = 0.f, acca = 0.f, accb = 0.f;

  for (int i = beg; i < end; i += 2) {
    const bool two = (i + 1 < end);
    int s0 = srcs[i];
    int s1 = two ? srcs[i + 1] : s0;
    float4 e0 = eaC[i];
    float4 e1 = two ? eaC[i + 1] : e0;
    bf162 q0 = *(const bf162*)(xl + (size_t)s0 * HC1 + ch);
    bf162 q1 = *(const bf162*)(xl + (size_t)s1 * HC1 + ch);
    {
      float xa = __bfloat162float(q0.x), xb = __bfloat162float(q0.y);
      float m0 = xa + xra + e0.x * w0a + e0.y * w1a + e0.z * w2a + e0.w * w3a;
      float m1 = xb + xrb + e0.x * w0b + e0.y * w1b + e0.z * w2b + e0.w * w3b;
      float p = ((m0 > 0.f) ? m0 : 0.2f * m0) * ata + ((m1 > 0.f) ? m1 : 0.2f * m1) * atb;
#pragma unroll
      for (int o = 1; o < 64; o <<= 1) p += __shfl_xor(p, o);
      float ex = __expf(p);
      den += ex; acca = fmaf(ex, xa, acca); accb = fmaf(ex, xb, accb);
    }
    if (two) {
      float xa = __bfloat162float(q1.x), xb = __bfloat162float(q1.y);
      float m0 = xa + xra + e1.x * w0a + e1.y * w1a + e1.z * w2a + e1.w * w3a;
      float m1 = xb + xrb + e1.x * w0b + e1.y * w1b + e1.z * w2b + e1.w * w3b;
      float p = ((m0 > 0.f) ? m0 : 0.2f * m0) * ata + ((m1 > 0.f) ? m1 : 0.2f * m1) * atb;
#pragma unroll
      for (int o = 1; o < 64; o <<= 1) p += __shfl_xor(p, o);
      float ex = __expf(p);
      den += ex; acca = fmaf(ex, xa, acca); accb = fmaf(ex, xb, accb);
    }
  }

  const float rden = 1.f / (den + 1e-16f);
  float va = acca * rden + bias[ch];
  float vb = accb * rden + bias[ch + 1];

  // LayerNorm over 512 channels (4 waves)
  __shared__ float2 red[4];
  float s1 = va + vb, s2 = va * va + vb * vb;
#pragma unroll
  for (int o = 1; o < 64; o <<= 1) { s1 += __shfl_xor(s1, o); s2 += __shfl_xor(s2, o); }
  if (lane == 0) red[wave] = make_float2(s1, s2);
  __syncthreads();
  float ts1 = red[0].x + red[1].x + red[2].x + red[3].x;
  float ts2 = red[0].y + red[1].y + red[2].y + red[3].y;
  float mu  = ts1 * (1.f / HC1);
  float var = ts2 * (1.f / HC1) - mu * mu;
  float rs  = rsqrtf(var + 1e-5f);
  float ya = (va - mu) * rs * g[ch] + be[ch];
  float yb = (vb - mu) * rs * g[ch + 1] + be[ch + 1];
  ya = (ya > 0.f) ? ya : expm1f(ya);
  yb = (yb > 0.f) ? yb : expm1f(yb);
  *(float2*)(h1 + (size_t)v * HC1 + ch) = make_float2(ya, yb);
}

// ---------------- layer 2 fused: scores + agg + bias + LN + residual -------
// one wave per node (4 nodes/block); lane covers 4 channels.
__global__ __launch_bounds__(256)
void fused2_kernel(const int* __restrict__ srcs, const float4* __restrict__ eaC,
                   const int* __restrict__ offs,
                   const bf16* __restrict__ xl, const bf16* __restrict__ xr,
                   const float* __restrict__ We, const float* __restrict__ att,
                   const float* __restrict__ bias, const float* __restrict__ g,
                   const float* __restrict__ be, const float* __restrict__ xin,
                   float* __restrict__ out, int N) {
  const int wave = threadIdx.x >> 6, lane = threadIdx.x & 63;
  const int v = blockIdx.x * 4 + wave;
  if (v >= N) return;
  const int c0 = lane * 4;

  float w[4][4];
#pragma unroll
  for (int k = 0; k < 4; k++) {
    float4 q = *(const float4*)(We + k * HC2 + c0);
    w[k][0] = q.x; w[k][1] = q.y; w[k][2] = q.z; w[k][3] = q.w;
  }
  float4 atv = *(const float4*)(att + c0);
  float at[4] = {atv.x, atv.y, atv.z, atv.w};
  const bf162* rp = (const bf162*)(xr + (size_t)v * HC2 + c0);
  bf162 r0 = rp[0], r1 = rp[1];
  float xrv[4] = {__bfloat162float(r0.x), __bfloat162float(r0.y),
                  __bfloat162float(r1.x), __bfloat162float(r1.y)};

  const int beg = offs[v], end = offs[v + 1];
  float den = 0.f, acc[4] = {0.f, 0.f, 0.f, 0.f};

  for (int i = beg; i < end; i += 2) {
    const bool two = (i + 1 < end);
    int s0 = srcs[i];
    int s1 = two ? srcs[i + 1] : s0;
    float4 e0 = eaC[i];
    float4 e1 = two ? eaC[i + 1] : e0;
    const bf162* p0 = (const bf162*)(xl + (size_t)s0 * HC2 + c0);
    const bf162* p1 = (const bf162*)(xl + (size_t)s1 * HC2 + c0);
    bf162 qa0 = p0[0], qa1 = p0[1];
    bf162 qb0 = p1[0], qb1 = p1[1];
    {
      float xa[4] = {__bfloat162float(qa0.x), __bfloat162float(qa0.y),
                     __bfloat162float(qa1.x), __bfloat162float(qa1.y)};
      float p = 0.f;
#pragma unroll
      for (int j = 0; j < 4; j++) {
        float m = xa[j] + xrv[j] + e0.x * w[0][j] + e0.y * w[1][j] + e0.z * w[2][j] + e0.w * w[3][j];
        p = fmaf((m > 0.f) ? m : 0.2f * m, at[j], p);
      }
#pragma unroll
      for (int o = 1; o < 64; o <<= 1) p += __shfl_xor(p, o);
      float ex = __expf(p);
      den += ex;
#pragma unroll
      for (int j = 0; j < 4; j++) acc[j] = fmaf(ex, xa[j], acc[j]);
    }
    if (two) {
      float xa[4] = {__bfloat162float(qb0.x), __bfloat162float(qb0.y),
                     __bfloat162float(qb1.x), __bfloat162float(qb1.y)};
      float p = 0.f;
#pragma unroll
      for (int j = 0; j < 4; j++) {
        float m = xa[j] + xrv[j] + e1.x * w[0][j] + e1.y * w[1][j] + e1.z * w[2][j] + e1.w * w[3][j];
        p = fmaf((m > 0.f) ? m : 0.2f * m, at[j], p);
      }
#pragma unroll
      for (int o = 1; o < 64; o <<= 1) p += __shfl_xor(p, o);
      float ex = __expf(p);
      den += ex;
#pragma unroll
      for (int j = 0; j < 4; j++) acc[j] = fmaf(ex, xa[j], acc[j]);
    }
  }

  const float rden = 1.f / (den + 1e-16f);
  float4 bv = *(const float4*)(bias + c0);
  float val[4] = {acc[0] * rden + bv.x, acc[1] * rden + bv.y,
                  acc[2] * rden + bv.z, acc[3] * rden + bv.w};

  float s1 = val[0] + val[1] + val[2] + val[3];
  float s2 = val[0] * val[0] + val[1] * val[1] + val[2] * val[2] + val[3] * val[3];
#pragma unroll
  for (int o = 1; o < 64; o <<= 1) { s1 += __shfl_xor(s1, o); s2 += __shfl_xor(s2, o); }
  float mu  = s1 * (1.f / HC2);
  float var = s2 * (1.f / HC2) - mu * mu;
  float rs  = rsqrtf(var + 1e-5f);
  float4 gv = *(const float4*)(g + c0);
  float4 ev = *(const float4*)(be + c0);
  float4 xv = *(const float4*)(xin + (size_t)v * HC2 + c0);
  float4 o4;
  o4.x = (val[0] - mu) * rs * gv.x + ev.x + xv.x;
  o4.y = (val[1] - mu) * rs * gv.y + ev.y + xv.y;
  o4.z = (val[2] - mu) * rs * gv.z + ev.z + xv.z;
  o4.w = (val[3] - mu) * rs * gv.w + ev.w + xv.w;
  *(float4*)(out + (size_t)v * HC2 + c0) = o4;
}

// ---------------------------------------------------------------------------
extern "C" void kernel_launch(void* const* d_in, const int* in_sizes, int n_in,
                              void* d_out, int out_size, void* d_ws, size_t ws_size,
                              hipStream_t stream) {
  const float* x     = (const float*)d_in[0];
  const int*   ei    = (const int*)d_in[1];
  const float* eattr = (const float*)d_in[2];
  const float* Wl1   = (const float*)d_in[3];
  const float* Wr1   = (const float*)d_in[4];
  const float* We1   = (const float*)d_in[5];
  const float* att1  = (const float*)d_in[6];
  const float* b1    = (const float*)d_in[7];
  const float* g1    = (const float*)d_in[8];
  const float* be1   = (const float*)d_in[9];
  const float* Wl2   = (const float*)d_in[10];
  const float* Wr2   = (const float*)d_in[11];
  const float* We2   = (const float*)d_in[12];
  const float* att2  = (const float*)d_in[13];
  const float* b2    = (const float*)d_in[14];
  const float* g2    = (const float*)d_in[15];
  const float* be2   = (const float*)d_in[16];

  const int N    = in_sizes[0] / D_IN;   // 10000
  const int E    = in_sizes[2] / 4;      // 320000
  const int Etot = E + N;

  char* w = (char*)d_ws;
  auto alloc = [&](size_t bytes) -> void* {
    void* p = (void*)w;
    w += (bytes + 255) & ~(size_t)255;
    return p;
  };
  bf16*   xl1   = (bf16*)alloc((size_t)N * HC1 * 2);
  bf16*   xr1   = (bf16*)alloc((size_t)N * HC1 * 2);
  float*  h1    = (float*)alloc((size_t)N * HC1 * 4);
  bf16*   xl2   = (bf16*)alloc((size_t)N * HC2 * 2);
  bf16*   xr2   = (bf16*)alloc((size_t)N * HC2 * 2);
  int*    srcs  = (int*)alloc((size_t)Etot * 4);
  float4* eaC   = (float4*)alloc((size_t)Etot * 16);
  int*    offs  = (int*)alloc((size_t)(N + 1) * 4);
  float*  mean4 = (float*)alloc(64);
  char*   zb    = w;                     // zeroed region
  int*    counts = (int*)alloc((size_t)N * 4);
  int*    cursor = (int*)alloc((size_t)N * 4);
  float*  sums   = (float*)alloc(64);
  size_t  zbytes = (size_t)(w - zb);

  hipMemsetAsync(zb, 0, zbytes, stream);

  mean_kernel<<<256, 256, 0, stream>>>(eattr, sums, E);
  meanw_kernel<<<1, 64, 0, stream>>>(sums, mean4, 1.f / (float)E);

  count_kernel<<<1024, 256, 0, stream>>>(ei, counts, E, Etot);
  scan_kernel<<<1, 1024, 0, stream>>>(counts, offs, N);
  fill_kernel<<<1024, 256, 0, stream>>>(ei, offs, cursor, eattr, mean4, srcs, eaC, E, Etot);

  dim3 gg1(HC1 / GTN, (N + GTM - 1) / GTM);
  gemm_kernel<bf16><<<gg1, 256, 0, stream>>>(x, Wl1, xl1, N, D_IN, HC1);
  gemm_kernel<bf16><<<gg1, 256, 0, stream>>>(x, Wr1, xr1, N, D_IN, HC1);

  fused1_kernel<<<N, 256, 0, stream>>>(srcs, eaC, offs, xl1, xr1, We1, att1, b1, g1, be1, h1);

  dim3 gg2(HC2 / GTN, (N + GTM - 1) / GTM);
  gemm_kernel<bf16><<<gg2, 256, 0, stream>>>(h1, Wl2, xl2, N, HC1, HC2);
  gemm_kernel<bf16><<<gg2, 256, 0, stream>>>(h1, Wr2, xr2, N, HC1, HC2);

  fused2_kernel<<<(N + 3) / 4, 256, 0, stream>>>(srcs, eaC, offs, xl2, xr2, We2, att2,
                                                 b2, g2, be2, x, (float*)d_out, N);
}

// Round 3
// 385.219 us; speedup vs baseline: 2.8576x; 1.8168x over previous
//
#include <hip/hip_runtime.h>
#include <hip/hip_bf16.h>

#define HC1 512   // layer-1 heads*channels (4*128)
#define HC2 256   // layer-2 (1*256)
#define D_IN 256

typedef __hip_bfloat16  bf16;
typedef __hip_bfloat162 bf162;
typedef __attribute__((ext_vector_type(8))) short short8;   // 8 bf16 = 4 VGPR
typedef __attribute__((ext_vector_type(4))) float f32x4;

// ------------------------- async global->LDS (16B/lane) --------------------
__device__ __forceinline__ void glds16(const bf16* g, bf16* l) {
#if __has_builtin(__builtin_amdgcn_global_load_lds)
  __builtin_amdgcn_global_load_lds(
      (const __attribute__((address_space(1))) void*)g,
      (__attribute__((address_space(3))) void*)l, 16, 0, 0);
#else
  int lane = threadIdx.x & 63;
  ((int4*)l)[lane] = *(const int4*)g;
#endif
}

// ------------------------- bf16 MFMA GEMM ----------------------------------
// C[M,N] = A[M,K] @ B[K,N], B given pre-transposed as BT[N,K]. bf16 in/out,
// f32 accumulate. Tile 128x128, BK=32, 4 waves (2x2), each wave 64x64.
// LDS k-chunk-major: As[kc][row][8], Bs[kc][col][8] -> lane-contiguous
// ds_read_b128 (conflict-free) and lane-linear global_load_lds staging.
__global__ __launch_bounds__(256)
void gemm_mfma_kernel(const bf16* __restrict__ A, const bf16* __restrict__ BT,
                      bf16* __restrict__ C, int M, int K, int N) {
  __shared__ bf16 lds[8192];           // 16 KiB: A [0,4096), B [4096,8192)
  const int t = threadIdx.x;
  const int w  = t >> 6, l = t & 63;
  const int wr = w >> 1, wc = w & 1;
  const int lo = l & 15, hi = l >> 4;
  const int m0 = blockIdx.y * 128;
  const int n0 = blockIdx.x * 128;

  f32x4 acc[4][4] = {};

  // two staging chunks (1 KiB each) per wave for A and for B
  const int c0 = w * 2, c1 = w * 2 + 1;
  const int kc0 = c0 >> 1, r0 = (c0 & 1) * 64 + l;
  const int kc1 = c1 >> 1, r1 = (c1 & 1) * 64 + l;
  int mr0 = m0 + r0; if (mr0 >= M) mr0 = M - 1;   // clamp: no OOB reads
  int mr1 = m0 + r1; if (mr1 >= M) mr1 = M - 1;
  const bf16* ga0 = A + (size_t)mr0 * K + kc0 * 8;
  const bf16* ga1 = A + (size_t)mr1 * K + kc1 * 8;
  const bf16* gb0 = BT + (size_t)(n0 + r0) * K + kc0 * 8;
  const bf16* gb1 = BT + (size_t)(n0 + r1) * K + kc1 * 8;
  bf16* la0 = &lds[c0 * 512];
  bf16* la1 = &lds[c1 * 512];
  bf16* lb0 = &lds[4096 + c0 * 512];
  bf16* lb1 = &lds[4096 + c1 * 512];

  for (int k0 = 0; k0 < K; k0 += 32) {
    if (k0) __syncthreads();
    glds16(ga0 + k0, la0);
    glds16(ga1 + k0, la1);
    glds16(gb0 + k0, lb0);
    glds16(gb1 + k0, lb1);
    __syncthreads();                    // drains vmcnt before use

    short8 af[4], bfr[4];
#pragma unroll
    for (int f = 0; f < 4; f++) {
      af[f]  = *(const short8*)&lds[hi * 1024 + (wr * 64 + f * 16 + lo) * 8];
      bfr[f] = *(const short8*)&lds[4096 + hi * 1024 + (wc * 64 + f * 16 + lo) * 8];
    }
#pragma unroll
    for (int fm = 0; fm < 4; fm++)
#pragma unroll
      for (int fn = 0; fn < 4; fn++)
        acc[fm][fn] = __builtin_amdgcn_mfma_f32_16x16x32_bf16(af[fm], bfr[fn],
                                                              acc[fm][fn], 0, 0, 0);
  }

#pragma unroll
  for (int fm = 0; fm < 4; fm++) {
#pragma unroll
    for (int r = 0; r < 4; r++) {
      int row = m0 + wr * 64 + fm * 16 + hi * 4 + r;
      if (row < M) {
#pragma unroll
        for (int fn = 0; fn < 4; fn++) {
          int col = n0 + wc * 64 + fn * 16 + lo;
          C[(size_t)row * N + col] = __float2bfloat16(acc[fm][fn][r]);
        }
      }
    }
  }
}

// ------------------------- prep: x -> bf16 ---------------------------------
__global__ void convx_kernel(const float* __restrict__ x, bf16* __restrict__ xb, int n4) {
  int i = blockIdx.x * blockDim.x + threadIdx.x;
  if (i >= n4) return;
  float4 v = ((const float4*)x)[i];
  union { bf16 h[4]; uint2 u; } cv;
  cv.h[0] = __float2bfloat16(v.x); cv.h[1] = __float2bfloat16(v.y);
  cv.h[2] = __float2bfloat16(v.z); cv.h[3] = __float2bfloat16(v.w);
  ((uint2*)xb)[i] = cv.u;
}

// prep: W1T[n][k] = [Wl1|Wr1]^T (1024x256), W2T[n][k] = [Wl2|Wr2]^T (512x512)
__global__ void prepw_kernel(const float* __restrict__ Wl1, const float* __restrict__ Wr1,
                             const float* __restrict__ Wl2, const float* __restrict__ Wr2,
                             bf16* __restrict__ W1T, bf16* __restrict__ W2T) {
  int i = blockIdx.x * blockDim.x + threadIdx.x;
  const int n1 = 1024 * 256;
  if (i < n1) {
    int n = i >> 8, k = i & 255;
    float v = (n < 512) ? Wl1[(size_t)k * 512 + n] : Wr1[(size_t)k * 512 + (n - 512)];
    W1T[i] = __float2bfloat16(v);
  } else if (i < n1 + 512 * 512) {
    int j = i - n1;
    int n = j >> 9, k = j & 511;
    float v = (n < 256) ? Wl2[(size_t)k * 256 + n] : Wr2[(size_t)k * 256 + (n - 256)];
    W2T[j] = __float2bfloat16(v);
  }
}

// ------------------------- edge-attr mean ----------------------------------
__global__ void mean_kernel(const float* __restrict__ eattr, float* __restrict__ sums, int E) {
  int tid = blockIdx.x * blockDim.x + threadIdx.x;
  int stride = gridDim.x * blockDim.x;
  float l0 = 0.f, l1 = 0.f, l2 = 0.f, l3 = 0.f;
  for (int e = tid; e < E; e += stride) {
    float4 v = ((const float4*)eattr)[e];
    l0 += v.x; l1 += v.y; l2 += v.z; l3 += v.w;
  }
#pragma unroll
  for (int o = 1; o < 64; o <<= 1) {
    l0 += __shfl_xor(l0, o); l1 += __shfl_xor(l1, o);
    l2 += __shfl_xor(l2, o); l3 += __shfl_xor(l3, o);
  }
  if ((threadIdx.x & 63) == 0) {
    atomicAdd(&sums[0], l0); atomicAdd(&sums[1], l1);
    atomicAdd(&sums[2], l2); atomicAdd(&sums[3], l3);
  }
}

__global__ void meanw_kernel(const float* __restrict__ sums, float* __restrict__ mean4, float invE) {
  int t = threadIdx.x;
  if (t < 4) mean4[t] = sums[t] * invE;
}

// ------------------------- CSR build ---------------------------------------
__global__ void count_kernel(const int* __restrict__ ei, int* __restrict__ counts, int E, int Etot) {
  int tid = blockIdx.x * blockDim.x + threadIdx.x;
  int stride = gridDim.x * blockDim.x;
  for (int e = tid; e < Etot; e += stride) {
    int dst = (e < E) ? ei[E + e] : (e - E);
    atomicAdd(&counts[dst], 1);
  }
}

__global__ __launch_bounds__(1024)
void scan_kernel(const int* __restrict__ counts, int* __restrict__ offs, int N) {
  __shared__ int wsum[16];
  int tid = threadIdx.x, wid = tid >> 6, lane = tid & 63;
  if (tid == 0) offs[0] = 0;
  int carry = 0;
  for (int base = 0; base < N; base += 1024) {
    int i = base + tid;
    int v = (i < N) ? counts[i] : 0;
    int s = v;
#pragma unroll
    for (int o = 1; o < 64; o <<= 1) {
      int u = __shfl_up(s, o);
      if (lane >= o) s += u;
    }
    if (lane == 63) wsum[wid] = s;
    __syncthreads();
    if (wid == 0) {
      int t2 = (lane < 16) ? wsum[lane] : 0;
#pragma unroll
      for (int o = 1; o < 16; o <<= 1) {
        int u = __shfl_up(t2, o);
        if (lane >= o) t2 += u;
      }
      if (lane < 16) wsum[lane] = t2;
    }
    __syncthreads();
    int pre = (wid > 0) ? wsum[wid - 1] : 0;
    int tot = wsum[15];
    if (i < N) offs[i + 1] = carry + pre + s;
    carry += tot;
    __syncthreads();
  }
}

__global__ void fill_kernel(const int* __restrict__ ei, const int* __restrict__ offs,
                            int* __restrict__ cursor, const float* __restrict__ eattr,
                            const float* __restrict__ mean4, int* __restrict__ srcs,
                            float4* __restrict__ eaC, int E, int Etot) {
  int tid = blockIdx.x * blockDim.x + threadIdx.x;
  int stride = gridDim.x * blockDim.x;
  for (int e = tid; e < Etot; e += stride) {
    int src, dst;
    if (e < E) { src = ei[e]; dst = ei[E + e]; } else { src = e - E; dst = src; }
    int pos = atomicAdd(&cursor[dst], 1);
    int slot = offs[dst] + pos;
    srcs[slot] = src;
    eaC[slot] = (e < E) ? ((const float4*)eattr)[e] : *(const float4*)mean4;
  }
}

// ---------------- layer 1 fused: scores + softmax-agg + bias + LN + ELU ----
// one block (256 thr) per node; wave = head; lane covers 2 channels.
// xlr: [N][1024] bf16 = [xl(512) | xr(512)]
__global__ __launch_bounds__(256)
void fused1_kernel(const int* __restrict__ srcs, const float4* __restrict__ eaC,
                   const int* __restrict__ offs, const bf16* __restrict__ xlr,
                   const float* __restrict__ We, const float* __restrict__ att,
                   const float* __restrict__ bias, const float* __restrict__ g,
                   const float* __restrict__ be, bf16* __restrict__ h1) {
  const int v = blockIdx.x;
  const int t = threadIdx.x;
  const int wave = t >> 6, lane = t & 63;
  const int ch = wave * 128 + lane * 2;

  const float w0a = We[0 * HC1 + ch], w0b = We[0 * HC1 + ch + 1];
  const float w1a = We[1 * HC1 + ch], w1b = We[1 * HC1 + ch + 1];
  const float w2a = We[2 * HC1 + ch], w2b = We[2 * HC1 + ch + 1];
  const float w3a = We[3 * HC1 + ch], w3b = We[3 * HC1 + ch + 1];
  const float ata = att[ch], atb = att[ch + 1];
  bf162 xrv = *(const bf162*)(xlr + (size_t)v * 1024 + 512 + ch);
  const float xra = __bfloat162float(xrv.x), xrb = __bfloat162float(xrv.y);

  const int beg = offs[v], end = offs[v + 1];
  float den = 0.f, acca = 0.f, accb = 0.f;

  for (int i = beg; i < end; i += 2) {
    const bool two = (i + 1 < end);
    int s0 = srcs[i];
    int s1 = two ? srcs[i + 1] : s0;
    float4 e0 = eaC[i];
    float4 e1 = two ? eaC[i + 1] : e0;
    bf162 q0 = *(const bf162*)(xlr + (size_t)s0 * 1024 + ch);
    bf162 q1 = *(const bf162*)(xlr + (size_t)s1 * 1024 + ch);
    {
      float xa = __bfloat162float(q0.x), xb = __bfloat162float(q0.y);
      float m0 = xa + xra + e0.x * w0a + e0.y * w1a + e0.z * w2a + e0.w * w3a;
      float m1 = xb + xrb + e0.x * w0b + e0.y * w1b + e0.z * w2b + e0.w * w3b;
      float p = ((m0 > 0.f) ? m0 : 0.2f * m0) * ata + ((m1 > 0.f) ? m1 : 0.2f * m1) * atb;
#pragma unroll
      for (int o = 1; o < 64; o <<= 1) p += __shfl_xor(p, o);
      float ex = __expf(p);
      den += ex; acca = fmaf(ex, xa, acca); accb = fmaf(ex, xb, accb);
    }
    if (two) {
      float xa = __bfloat162float(q1.x), xb = __bfloat162float(q1.y);
      float m0 = xa + xra + e1.x * w0a + e1.y * w1a + e1.z * w2a + e1.w * w3a;
      float m1 = xb + xrb + e1.x * w0b + e1.y * w1b + e1.z * w2b + e1.w * w3b;
      float p = ((m0 > 0.f) ? m0 : 0.2f * m0) * ata + ((m1 > 0.f) ? m1 : 0.2f * m1) * atb;
#pragma unroll
      for (int o = 1; o < 64; o <<= 1) p += __shfl_xor(p, o);
      float ex = __expf(p);
      den += ex; acca = fmaf(ex, xa, acca); accb = fmaf(ex, xb, accb);
    }
  }

  const float rden = 1.f / (den + 1e-16f);
  float va = acca * rden + bias[ch];
  float vb = accb * rden + bias[ch + 1];

  __shared__ float2 red[4];
  float s1 = va + vb, s2 = va * va + vb * vb;
#pragma unroll
  for (int o = 1; o < 64; o <<= 1) { s1 += __shfl_xor(s1, o); s2 += __shfl_xor(s2, o); }
  if (lane == 0) red[wave] = make_float2(s1, s2);
  __syncthreads();
  float ts1 = red[0].x + red[1].x + red[2].x + red[3].x;
  float ts2 = red[0].y + red[1].y + red[2].y + red[3].y;
  float mu  = ts1 * (1.f / HC1);
  float var = ts2 * (1.f / HC1) - mu * mu;
  float rs  = rsqrtf(var + 1e-5f);
  float ya = (va - mu) * rs * g[ch] + be[ch];
  float yb = (vb - mu) * rs * g[ch + 1] + be[ch + 1];
  ya = (ya > 0.f) ? ya : expm1f(ya);
  yb = (yb > 0.f) ? yb : expm1f(yb);
  bf162 hv;
  hv.x = __float2bfloat16(ya); hv.y = __float2bfloat16(yb);
  *(bf162*)(h1 + (size_t)v * HC1 + ch) = hv;
}

// ---------------- layer 2 fused: scores + agg + bias + LN + residual -------
// one wave per node (4 nodes/block); lane covers 4 channels.
// xlr: [N][512] bf16 = [xl(256) | xr(256)]
__global__ __launch_bounds__(256)
void fused2_kernel(const int* __restrict__ srcs, const float4* __restrict__ eaC,
                   const int* __restrict__ offs, const bf16* __restrict__ xlr,
                   const float* __restrict__ We, const float* __restrict__ att,
                   const float* __restrict__ bias, const float* __restrict__ g,
                   const float* __restrict__ be, const float* __restrict__ xin,
                   float* __restrict__ out, int N) {
  const int wave = threadIdx.x >> 6, lane = threadIdx.x & 63;
  const int v = blockIdx.x * 4 + wave;
  if (v >= N) return;
  const int c0 = lane * 4;

  float w[4][4];
#pragma unroll
  for (int k = 0; k < 4; k++) {
    float4 q = *(const float4*)(We + k * HC2 + c0);
    w[k][0] = q.x; w[k][1] = q.y; w[k][2] = q.z; w[k][3] = q.w;
  }
  float4 atv = *(const float4*)(att + c0);
  float at[4] = {atv.x, atv.y, atv.z, atv.w};
  const bf162* rp = (const bf162*)(xlr + (size_t)v * 512 + 256 + c0);
  bf162 r0 = rp[0], r1 = rp[1];
  float xrv[4] = {__bfloat162float(r0.x), __bfloat162float(r0.y),
                  __bfloat162float(r1.x), __bfloat162float(r1.y)};

  const int beg = offs[v], end = offs[v + 1];
  float den = 0.f, acc[4] = {0.f, 0.f, 0.f, 0.f};

  for (int i = beg; i < end; i += 2) {
    const bool two = (i + 1 < end);
    int s0 = srcs[i];
    int s1 = two ? srcs[i + 1] : s0;
    float4 e0 = eaC[i];
    float4 e1 = two ? eaC[i + 1] : e0;
    const bf162* p0 = (const bf162*)(xlr + (size_t)s0 * 512 + c0);
    const bf162* p1 = (const bf162*)(xlr + (size_t)s1 * 512 + c0);
    bf162 qa0 = p0[0], qa1 = p0[1];
    bf162 qb0 = p1[0], qb1 = p1[1];
    {
      float xa[4] = {__bfloat162float(qa0.x), __bfloat162float(qa0.y),
                     __bfloat162float(qa1.x), __bfloat162float(qa1.y)};
      float p = 0.f;
#pragma unroll
      for (int j = 0; j < 4; j++) {
        float m = xa[j] + xrv[j] + e0.x * w[0][j] + e0.y * w[1][j] + e0.z * w[2][j] + e0.w * w[3][j];
        p = fmaf((m > 0.f) ? m : 0.2f * m, at[j], p);
      }
#pragma unroll
      for (int o = 1; o < 64; o <<= 1) p += __shfl_xor(p, o);
      float ex = __expf(p);
      den += ex;
#pragma unroll
      for (int j = 0; j < 4; j++) acc[j] = fmaf(ex, xa[j], acc[j]);
    }
    if (two) {
      float xa[4] = {__bfloat162float(qb0.x), __bfloat162float(qb0.y),
                     __bfloat162float(qb1.x), __bfloat162float(qb1.y)};
      float p = 0.f;
#pragma unroll
      for (int j = 0; j < 4; j++) {
        float m = xa[j] + xrv[j] + e1.x * w[0][j] + e1.y * w[1][j] + e1.z * w[2][j] + e1.w * w[3][j];
        p = fmaf((m > 0.f) ? m : 0.2f * m, at[j], p);
      }
#pragma unroll
      for (int o = 1; o < 64; o <<= 1) p += __shfl_xor(p, o);
      float ex = __expf(p);
      den += ex;
#pragma unroll
      for (int j = 0; j < 4; j++) acc[j] = fmaf(ex, xa[j], acc[j]);
    }
  }

  const float rden = 1.f / (den + 1e-16f);
  float4 bv = *(const float4*)(bias + c0);
  float val[4] = {acc[0] * rden + bv.x, acc[1] * rden + bv.y,
                  acc[2] * rden + bv.z, acc[3] * rden + bv.w};

  float s1 = val[0] + val[1] + val[2] + val[3];
  float s2 = val[0] * val[0] + val[1] * val[1] + val[2] * val[2] + val[3] * val[3];
#pragma unroll
  for (int o = 1; o < 64; o <<= 1) { s1 += __shfl_xor(s1, o); s2 += __shfl_xor(s2, o); }
  float mu  = s1 * (1.f / HC2);
  float var = s2 * (1.f / HC2) - mu * mu;
  float rs  = rsqrtf(var + 1e-5f);
  float4 gv = *(const float4*)(g + c0);
  float4 ev = *(const float4*)(be + c0);
  float4 xv = *(const float4*)(xin + (size_t)v * HC2 + c0);
  float4 o4;
  o4.x = (val[0] - mu) * rs * gv.x + ev.x + xv.x;
  o4.y = (val[1] - mu) * rs * gv.y + ev.y + xv.y;
  o4.z = (val[2] - mu) * rs * gv.z + ev.z + xv.z;
  o4.w = (val[3] - mu) * rs * gv.w + ev.w + xv.w;
  *(float4*)(out + (size_t)v * HC2 + c0) = o4;
}

// ---------------------------------------------------------------------------
extern "C" void kernel_launch(void* const* d_in, const int* in_sizes, int n_in,
                              void* d_out, int out_size, void* d_ws, size_t ws_size,
                              hipStream_t stream) {
  const float* x     = (const float*)d_in[0];
  const int*   ei    = (const int*)d_in[1];
  const float* eattr = (const float*)d_in[2];
  const float* Wl1   = (const float*)d_in[3];
  const float* Wr1   = (const float*)d_in[4];
  const float* We1   = (const float*)d_in[5];
  const float* att1  = (const float*)d_in[6];
  const float* b1    = (const float*)d_in[7];
  const float* g1    = (const float*)d_in[8];
  const float* be1   = (const float*)d_in[9];
  const float* Wl2   = (const float*)d_in[10];
  const float* Wr2   = (const float*)d_in[11];
  const float* We2   = (const float*)d_in[12];
  const float* att2  = (const float*)d_in[13];
  const float* b2    = (const float*)d_in[14];
  const float* g2    = (const float*)d_in[15];
  const float* be2   = (const float*)d_in[16];

  const int N    = in_sizes[0] / D_IN;   // 10000
  const int E    = in_sizes[2] / 4;      // 320000
  const int Etot = E + N;

  char* w = (char*)d_ws;
  auto alloc = [&](size_t bytes) -> void* {
    void* p = (void*)w;
    w += (bytes + 255) & ~(size_t)255;
    return p;
  };
  bf16*   xb    = (bf16*)alloc((size_t)N * D_IN * 2);        // x in bf16
  bf16*   W1T   = (bf16*)alloc((size_t)1024 * 256 * 2);      // [Wl1|Wr1]^T
  bf16*   W2T   = (bf16*)alloc((size_t)512 * 512 * 2);       // [Wl2|Wr2]^T
  bf16*   xlr1  = (bf16*)alloc((size_t)N * 1024 * 2);        // [xl1|xr1]
  bf16*   h1    = (bf16*)alloc((size_t)N * HC1 * 2);
  bf16*   xlr2  = (bf16*)alloc((size_t)N * 512 * 2);         // [xl2|xr2]
  int*    srcs  = (int*)alloc((size_t)Etot * 4);
  float4* eaC   = (float4*)alloc((size_t)Etot * 16);
  int*    offs  = (int*)alloc((size_t)(N + 1) * 4);
  float*  mean4 = (float*)alloc(64);
  char*   zb    = w;                     // zeroed region
  int*    counts = (int*)alloc((size_t)N * 4);
  int*    cursor = (int*)alloc((size_t)N * 4);
  float*  sums   = (float*)alloc(64);
  size_t  zbytes = (size_t)(w - zb);

  hipMemsetAsync(zb, 0, zbytes, stream);

  // prep
  int n4 = N * D_IN / 4;
  convx_kernel<<<(n4 + 255) / 256, 256, 0, stream>>>(x, xb, n4);
  int wtot = 1024 * 256 + 512 * 512;
  prepw_kernel<<<(wtot + 255) / 256, 256, 0, stream>>>(Wl1, Wr1, Wl2, Wr2, W1T, W2T);

  mean_kernel<<<256, 256, 0, stream>>>(eattr, sums, E);
  meanw_kernel<<<1, 64, 0, stream>>>(sums, mean4, 1.f / (float)E);

  count_kernel<<<1024, 256, 0, stream>>>(ei, counts, E, Etot);
  scan_kernel<<<1, 1024, 0, stream>>>(counts, offs, N);
  fill_kernel<<<1024, 256, 0, stream>>>(ei, offs, cursor, eattr, mean4, srcs, eaC, E, Etot);

  // layer 1: xlr1 = xb @ [Wl1|Wr1]  (M=N, K=256, N=1024)
  dim3 gg1(1024 / 128, (N + 127) / 128);
  gemm_mfma_kernel<<<gg1, 256, 0, stream>>>(xb, W1T, xlr1, N, 256, 1024);

  fused1_kernel<<<N, 256, 0, stream>>>(srcs, eaC, offs, xlr1, We1, att1, b1, g1, be1, h1);

  // layer 2: xlr2 = h1 @ [Wl2|Wr2]  (M=N, K=512, N=512)
  dim3 gg2(512 / 128, (N + 127) / 128);
  gemm_mfma_kernel<<<gg2, 256, 0, stream>>>(h1, W2T, xlr2, N, 512, 512);

  fused2_kernel<<<(N + 3) / 4, 256, 0, stream>>>(srcs, eaC, offs, xlr2, We2, att2,
                                                 b2, g2, be2, x, (float*)d_out, N);
}

// Round 4
// 342.355 us; speedup vs baseline: 3.2154x; 1.1252x over previous
//
#include <hip/hip_runtime.h>
#include <hip/hip_bf16.h>

#define HC1 512   // layer-1 heads*channels (4*128)
#define HC2 256   // layer-2 (1*256)
#define D_IN 256

typedef __hip_bfloat16  bf16;
typedef __hip_bfloat162 bf162;
typedef __attribute__((ext_vector_type(8))) short short8;   // 8 bf16 = 4 VGPR
typedef __attribute__((ext_vector_type(4))) float f32x4;

__device__ __forceinline__ void unpack8(short8 q, float* x) {
  union { short8 s; bf162 h[4]; } u; u.s = q;
#pragma unroll
  for (int j = 0; j < 4; j++) {
    x[2 * j]     = __bfloat162float(u.h[j].x);
    x[2 * j + 1] = __bfloat162float(u.h[j].y);
  }
}

// ------------------------- async global->LDS (16B/lane) --------------------
__device__ __forceinline__ void glds16(const bf16* g, bf16* l) {
#if __has_builtin(__builtin_amdgcn_global_load_lds)
  __builtin_amdgcn_global_load_lds(
      (const __attribute__((address_space(1))) void*)g,
      (__attribute__((address_space(3))) void*)l, 16, 0, 0);
#else
  int lane = threadIdx.x & 63;
  ((int4*)l)[lane] = *(const int4*)g;
#endif
}

// ------------------------- bf16 MFMA GEMM ----------------------------------
// C[M,N] = A[M,K] @ BT[N,K]^T. Tile 128x128, BK=32, 4 waves, 64x64 each.
__global__ __launch_bounds__(256)
void gemm_mfma_kernel(const bf16* __restrict__ A, const bf16* __restrict__ BT,
                      bf16* __restrict__ C, int M, int K, int N) {
  __shared__ bf16 lds[8192];           // 16 KiB: A [0,4096), B [4096,8192)
  const int t = threadIdx.x;
  const int w  = t >> 6, l = t & 63;
  const int wr = w >> 1, wc = w & 1;
  const int lo = l & 15, hi = l >> 4;
  const int m0 = blockIdx.y * 128;
  const int n0 = blockIdx.x * 128;

  f32x4 acc[4][4] = {};

  const int c0 = w * 2, c1 = w * 2 + 1;
  const int kc0 = c0 >> 1, r0 = (c0 & 1) * 64 + l;
  const int kc1 = c1 >> 1, r1 = (c1 & 1) * 64 + l;
  int mr0 = m0 + r0; if (mr0 >= M) mr0 = M - 1;
  int mr1 = m0 + r1; if (mr1 >= M) mr1 = M - 1;
  const bf16* ga0 = A + (size_t)mr0 * K + kc0 * 8;
  const bf16* ga1 = A + (size_t)mr1 * K + kc1 * 8;
  const bf16* gb0 = BT + (size_t)(n0 + r0) * K + kc0 * 8;
  const bf16* gb1 = BT + (size_t)(n0 + r1) * K + kc1 * 8;
  bf16* la0 = &lds[c0 * 512];
  bf16* la1 = &lds[c1 * 512];
  bf16* lb0 = &lds[4096 + c0 * 512];
  bf16* lb1 = &lds[4096 + c1 * 512];

  for (int k0 = 0; k0 < K; k0 += 32) {
    if (k0) __syncthreads();
    glds16(ga0 + k0, la0);
    glds16(ga1 + k0, la1);
    glds16(gb0 + k0, lb0);
    glds16(gb1 + k0, lb1);
    __syncthreads();

    short8 af[4], bfr[4];
#pragma unroll
    for (int f = 0; f < 4; f++) {
      af[f]  = *(const short8*)&lds[hi * 1024 + (wr * 64 + f * 16 + lo) * 8];
      bfr[f] = *(const short8*)&lds[4096 + hi * 1024 + (wc * 64 + f * 16 + lo) * 8];
    }
#pragma unroll
    for (int fm = 0; fm < 4; fm++)
#pragma unroll
      for (int fn = 0; fn < 4; fn++)
        acc[fm][fn] = __builtin_amdgcn_mfma_f32_16x16x32_bf16(af[fm], bfr[fn],
                                                              acc[fm][fn], 0, 0, 0);
  }

#pragma unroll
  for (int fm = 0; fm < 4; fm++) {
#pragma unroll
    for (int r = 0; r < 4; r++) {
      int row = m0 + wr * 64 + fm * 16 + hi * 4 + r;
      if (row < M) {
#pragma unroll
        for (int fn = 0; fn < 4; fn++) {
          int col = n0 + wc * 64 + fn * 16 + lo;
          C[(size_t)row * N + col] = __float2bfloat16(acc[fm][fn][r]);
        }
      }
    }
  }
}

// ------------------------- prep: x -> bf16 ---------------------------------
__global__ void convx_kernel(const float* __restrict__ x, bf16* __restrict__ xb, int n4) {
  int i = blockIdx.x * blockDim.x + threadIdx.x;
  if (i >= n4) return;
  float4 v = ((const float4*)x)[i];
  union { bf16 h[4]; uint2 u; } cv;
  cv.h[0] = __float2bfloat16(v.x); cv.h[1] = __float2bfloat16(v.y);
  cv.h[2] = __float2bfloat16(v.z); cv.h[3] = __float2bfloat16(v.w);
  ((uint2*)xb)[i] = cv.u;
}

// tiled LDS transpose: out[n][k] = bf16(in[k][n]); 4 jobs via blockIdx.z
__global__ __launch_bounds__(256)
void transw_kernel(const float* __restrict__ Wl1, const float* __restrict__ Wr1,
                   const float* __restrict__ Wl2, const float* __restrict__ Wr2,
                   bf16* __restrict__ W1T, bf16* __restrict__ W2T) {
  __shared__ float tile[32][33];
  const int z = blockIdx.z;
  const float* in; bf16* out; int K, Nn;
  if (z == 0)      { in = Wl1; out = W1T;             K = 256; Nn = 512; }
  else if (z == 1) { in = Wr1; out = W1T + 512 * 256; K = 256; Nn = 512; }
  else if (z == 2) { in = Wl2; out = W2T;             K = 512; Nn = 256; }
  else             { in = Wr2; out = W2T + 256 * 512; K = 512; Nn = 256; }
  const int nt = blockIdx.x * 32, kt = blockIdx.y * 32;
  if (nt >= Nn || kt >= K) return;
  const int tx = threadIdx.x & 31, ty = threadIdx.x >> 5;
#pragma unroll
  for (int j = 0; j < 4; j++)
    tile[ty + j * 8][tx] = in[(size_t)(kt + ty + j * 8) * Nn + nt + tx];
  __syncthreads();
#pragma unroll
  for (int j = 0; j < 4; j++)
    out[(size_t)(nt + ty + j * 8) * K + kt + tx] = __float2bfloat16(tile[tx][ty + j * 8]);
}

// ------------------------- edge-attr mean ----------------------------------
__global__ void mean_kernel(const float* __restrict__ eattr, float* __restrict__ sums, int E) {
  int tid = blockIdx.x * blockDim.x + threadIdx.x;
  int stride = gridDim.x * blockDim.x;
  float l0 = 0.f, l1 = 0.f, l2 = 0.f, l3 = 0.f;
  for (int e = tid; e < E; e += stride) {
    float4 v = ((const float4*)eattr)[e];
    l0 += v.x; l1 += v.y; l2 += v.z; l3 += v.w;
  }
#pragma unroll
  for (int o = 1; o < 64; o <<= 1) {
    l0 += __shfl_xor(l0, o); l1 += __shfl_xor(l1, o);
    l2 += __shfl_xor(l2, o); l3 += __shfl_xor(l3, o);
  }
  if ((threadIdx.x & 63) == 0) {
    atomicAdd(&sums[0], l0); atomicAdd(&sums[1], l1);
    atomicAdd(&sums[2], l2); atomicAdd(&sums[3], l3);
  }
}

__global__ void meanw_kernel(const float* __restrict__ sums, float* __restrict__ mean4, float invE) {
  int t = threadIdx.x;
  if (t < 4) mean4[t] = sums[t] * invE;
}

// ------------------------- CSR build ---------------------------------------
__global__ void count_kernel(const int* __restrict__ ei, int* __restrict__ counts, int E, int Etot) {
  int tid = blockIdx.x * blockDim.x + threadIdx.x;
  int stride = gridDim.x * blockDim.x;
  for (int e = tid; e < Etot; e += stride) {
    int dst = (e < E) ? ei[E + e] : (e - E);
    atomicAdd(&counts[dst], 1);
  }
}

__global__ __launch_bounds__(1024)
void scan_kernel(const int* __restrict__ counts, int* __restrict__ offs, int N) {
  __shared__ int wsum[16];
  int tid = threadIdx.x, wid = tid >> 6, lane = tid & 63;
  if (tid == 0) offs[0] = 0;
  int carry = 0;
  for (int base = 0; base < N; base += 1024) {
    int i = base + tid;
    int v = (i < N) ? counts[i] : 0;
    int s = v;
#pragma unroll
    for (int o = 1; o < 64; o <<= 1) {
      int u = __shfl_up(s, o);
      if (lane >= o) s += u;
    }
    if (lane == 63) wsum[wid] = s;
    __syncthreads();
    if (wid == 0) {
      int t2 = (lane < 16) ? wsum[lane] : 0;
#pragma unroll
      for (int o = 1; o < 16; o <<= 1) {
        int u = __shfl_up(t2, o);
        if (lane >= o) t2 += u;
      }
      if (lane < 16) wsum[lane] = t2;
    }
    __syncthreads();
    int pre = (wid > 0) ? wsum[wid - 1] : 0;
    int tot = wsum[15];
    if (i < N) offs[i + 1] = carry + pre + s;
    carry += tot;
    __syncthreads();
  }
}

__global__ void fill_kernel(const int* __restrict__ ei, const int* __restrict__ offs,
                            int* __restrict__ cursor, const float* __restrict__ eattr,
                            const float* __restrict__ mean4, int* __restrict__ srcs,
                            float4* __restrict__ eaC, int E, int Etot) {
  int tid = blockIdx.x * blockDim.x + threadIdx.x;
  int stride = gridDim.x * blockDim.x;
  for (int e = tid; e < Etot; e += stride) {
    int src, dst;
    if (e < E) { src = ei[e]; dst = ei[E + e]; } else { src = e - E; dst = src; }
    int pos = atomicAdd(&cursor[dst], 1);
    int slot = offs[dst] + pos;
    srcs[slot] = src;
    eaC[slot] = (e < E) ? ((const float4*)eattr)[e] : *(const float4*)mean4;
  }
}

// ---------------- layer 1 fused: one WAVE per node, 8 ch/lane --------------
// xlr: [N][1024] bf16 = [xl(512) | xr(512)]; head = lane>>4 (16 lanes/head).
__global__ __launch_bounds__(256)
void fused1_kernel(const int* __restrict__ srcs, const float4* __restrict__ eaC,
                   const int* __restrict__ offs, const bf16* __restrict__ xlr,
                   const float* __restrict__ We, const float* __restrict__ att,
                   const float* __restrict__ bias, const float* __restrict__ g,
                   const float* __restrict__ be, bf16* __restrict__ h1, int N) {
  const int wave = threadIdx.x >> 6, lane = threadIdx.x & 63;
  const int v = blockIdx.x * 4 + wave;
  if (v >= N) return;
  const int ch = lane * 8;

  float w0[8], w1[8], w2[8], w3[8], aw[8], xr[8];
  *(float4*)&w0[0] = *(const float4*)(We + 0 * HC1 + ch);
  *(float4*)&w0[4] = *(const float4*)(We + 0 * HC1 + ch + 4);
  *(float4*)&w1[0] = *(const float4*)(We + 1 * HC1 + ch);
  *(float4*)&w1[4] = *(const float4*)(We + 1 * HC1 + ch + 4);
  *(float4*)&w2[0] = *(const float4*)(We + 2 * HC1 + ch);
  *(float4*)&w2[4] = *(const float4*)(We + 2 * HC1 + ch + 4);
  *(float4*)&w3[0] = *(const float4*)(We + 3 * HC1 + ch);
  *(float4*)&w3[4] = *(const float4*)(We + 3 * HC1 + ch + 4);
  *(float4*)&aw[0] = *(const float4*)(att + ch);
  *(float4*)&aw[4] = *(const float4*)(att + ch + 4);
  unpack8(*(const short8*)(xlr + (size_t)v * 1024 + 512 + ch), xr);

  const int beg = offs[v], end = offs[v + 1];
  float den = 0.f;
  float acc[8] = {};

  for (int i = beg; i < end; i += 2) {
    const bool two = (i + 1 < end);
    int s0 = srcs[i];
    int s1 = two ? srcs[i + 1] : s0;
    float4 e0 = eaC[i];
    float4 e1 = two ? eaC[i + 1] : e0;
    short8 q0 = *(const short8*)(xlr + (size_t)s0 * 1024 + ch);
    short8 q1 = *(const short8*)(xlr + (size_t)s1 * 1024 + ch);
    {
      float xa[8]; unpack8(q0, xa);
      float p = 0.f;
#pragma unroll
      for (int j = 0; j < 8; j++) {
        float m = xa[j] + xr[j];
        m = fmaf(e0.x, w0[j], m); m = fmaf(e0.y, w1[j], m);
        m = fmaf(e0.z, w2[j], m); m = fmaf(e0.w, w3[j], m);
        p = fmaf(fmaxf(m, 0.2f * m), aw[j], p);
      }
      p += __shfl_xor(p, 1); p += __shfl_xor(p, 2);
      p += __shfl_xor(p, 4); p += __shfl_xor(p, 8);
      float ex = __expf(p);
      den += ex;
#pragma unroll
      for (int j = 0; j < 8; j++) acc[j] = fmaf(ex, xa[j], acc[j]);
    }
    if (two) {
      float xa[8]; unpack8(q1, xa);
      float p = 0.f;
#pragma unroll
      for (int j = 0; j < 8; j++) {
        float m = xa[j] + xr[j];
        m = fmaf(e1.x, w0[j], m); m = fmaf(e1.y, w1[j], m);
        m = fmaf(e1.z, w2[j], m); m = fmaf(e1.w, w3[j], m);
        p = fmaf(fmaxf(m, 0.2f * m), aw[j], p);
      }
      p += __shfl_xor(p, 1); p += __shfl_xor(p, 2);
      p += __shfl_xor(p, 4); p += __shfl_xor(p, 8);
      float ex = __expf(p);
      den += ex;
#pragma unroll
      for (int j = 0; j < 8; j++) acc[j] = fmaf(ex, xa[j], acc[j]);
    }
  }

  const float rden = 1.f / (den + 1e-16f);
  float val[8];
  {
    float bv[8];
    *(float4*)&bv[0] = *(const float4*)(bias + ch);
    *(float4*)&bv[4] = *(const float4*)(bias + ch + 4);
#pragma unroll
    for (int j = 0; j < 8; j++) val[j] = acc[j] * rden + bv[j];
  }

  // LayerNorm over 512 ch — full-wave reduce, no LDS
  float s1 = 0.f, s2 = 0.f;
#pragma unroll
  for (int j = 0; j < 8; j++) { s1 += val[j]; s2 += val[j] * val[j]; }
#pragma unroll
  for (int o = 1; o < 64; o <<= 1) { s1 += __shfl_xor(s1, o); s2 += __shfl_xor(s2, o); }
  float mu  = s1 * (1.f / HC1);
  float var = s2 * (1.f / HC1) - mu * mu;
  float rs  = rsqrtf(var + 1e-5f);

  float gv[8], ev[8];
  *(float4*)&gv[0] = *(const float4*)(g + ch);
  *(float4*)&gv[4] = *(const float4*)(g + ch + 4);
  *(float4*)&ev[0] = *(const float4*)(be + ch);
  *(float4*)&ev[4] = *(const float4*)(be + ch + 4);
  union { short8 s; bf162 h[4]; } outp;
#pragma unroll
  for (int j = 0; j < 4; j++) {
    float ya = (val[2 * j]     - mu) * rs * gv[2 * j]     + ev[2 * j];
    float yb = (val[2 * j + 1] - mu) * rs * gv[2 * j + 1] + ev[2 * j + 1];
    ya = (ya > 0.f) ? ya : expm1f(ya);
    yb = (yb > 0.f) ? yb : expm1f(yb);
    outp.h[j].x = __float2bfloat16(ya);
    outp.h[j].y = __float2bfloat16(yb);
  }
  *(short8*)(h1 + (size_t)v * HC1 + ch) = outp.s;
}

// ---------------- layer 2 fused: one wave per node, 4 ch/lane --------------
// xlr: [N][512] bf16 = [xl(256) | xr(256)]
__global__ __launch_bounds__(256)
void fused2_kernel(const int* __restrict__ srcs, const float4* __restrict__ eaC,
                   const int* __restrict__ offs, const bf16* __restrict__ xlr,
                   const float* __restrict__ We, const float* __restrict__ att,
                   const float* __restrict__ bias, const float* __restrict__ g,
                   const float* __restrict__ be, const float* __restrict__ xin,
                   float* __restrict__ out, int N) {
  const int wave = threadIdx.x >> 6, lane = threadIdx.x & 63;
  const int v = blockIdx.x * 4 + wave;
  if (v >= N) return;
  const int c0 = lane * 4;

  float w[4][4];
#pragma unroll
  for (int k = 0; k < 4; k++) {
    float4 q = *(const float4*)(We + k * HC2 + c0);
    w[k][0] = q.x; w[k][1] = q.y; w[k][2] = q.z; w[k][3] = q.w;
  }
  float4 atv = *(const float4*)(att + c0);
  float at[4] = {atv.x, atv.y, atv.z, atv.w};
  float xrv[4];
  {
    union { short4 s; bf162 h[2]; } u;
    u.s = *(const short4*)(xlr + (size_t)v * 512 + 256 + c0);
    xrv[0] = __bfloat162float(u.h[0].x); xrv[1] = __bfloat162float(u.h[0].y);
    xrv[2] = __bfloat162float(u.h[1].x); xrv[3] = __bfloat162float(u.h[1].y);
  }

  const int beg = offs[v], end = offs[v + 1];
  float den = 0.f, acc[4] = {0.f, 0.f, 0.f, 0.f};

  for (int i = beg; i < end; i += 2) {
    const bool two = (i + 1 < end);
    int s0 = srcs[i];
    int s1 = two ? srcs[i + 1] : s0;
    float4 e0 = eaC[i];
    float4 e1 = two ? eaC[i + 1] : e0;
    union { short4 s; bf162 h[2]; } ua, ub;
    ua.s = *(const short4*)(xlr + (size_t)s0 * 512 + c0);
    ub.s = *(const short4*)(xlr + (size_t)s1 * 512 + c0);
    {
      float xa[4] = {__bfloat162float(ua.h[0].x), __bfloat162float(ua.h[0].y),
                     __bfloat162float(ua.h[1].x), __bfloat162float(ua.h[1].y)};
      float p = 0.f;
#pragma unroll
      for (int j = 0; j < 4; j++) {
        float m = xa[j] + xrv[j];
        m = fmaf(e0.x, w[0][j], m); m = fmaf(e0.y, w[1][j], m);
        m = fmaf(e0.z, w[2][j], m); m = fmaf(e0.w, w[3][j], m);
        p = fmaf(fmaxf(m, 0.2f * m), at[j], p);
      }
#pragma unroll
      for (int o = 1; o < 64; o <<= 1) p += __shfl_xor(p, o);
      float ex = __expf(p);
      den += ex;
#pragma unroll
      for (int j = 0; j < 4; j++) acc[j] = fmaf(ex, xa[j], acc[j]);
    }
    if (two) {
      float xa[4] = {__bfloat162float(ub.h[0].x), __bfloat162float(ub.h[0].y),
                     __bfloat162float(ub.h[1].x), __bfloat162float(ub.h[1].y)};
      float p = 0.f;
#pragma unroll
      for (int j = 0; j < 4; j++) {
        float m = xa[j] + xrv[j];
        m = fmaf(e1.x, w[0][j], m); m = fmaf(e1.y, w[1][j], m);
        m = fmaf(e1.z, w[2][j], m); m = fmaf(e1.w, w[3][j], m);
        p = fmaf(fmaxf(m, 0.2f * m), at[j], p);
      }
#pragma unroll
      for (int o = 1; o < 64; o <<= 1) p += __shfl_xor(p, o);
      float ex = __expf(p);
      den += ex;
#pragma unroll
      for (int j = 0; j < 4; j++) acc[j] = fmaf(ex, xa[j], acc[j]);
    }
  }

  const float rden = 1.f / (den + 1e-16f);
  float4 bv = *(const float4*)(bias + c0);
  float val[4] = {acc[0] * rden + bv.x, acc[1] * rden + bv.y,
                  acc[2] * rden + bv.z, acc[3] * rden + bv.w};

  float s1 = val[0] + val[1] + val[2] + val[3];
  float s2 = val[0] * val[0] + val[1] * val[1] + val[2] * val[2] + val[3] * val[3];
#pragma unroll
  for (int o = 1; o < 64; o <<= 1) { s1 += __shfl_xor(s1, o); s2 += __shfl_xor(s2, o); }
  float mu  = s1 * (1.f / HC2);
  float var = s2 * (1.f / HC2) - mu * mu;
  float rs  = rsqrtf(var + 1e-5f);
  float4 gv = *(const float4*)(g + c0);
  float4 ev = *(const float4*)(be + c0);
  float4 xv = *(const float4*)(xin + (size_t)v * HC2 + c0);
  float4 o4;
  o4.x = (val[0] - mu) * rs * gv.x + ev.x + xv.x;
  o4.y = (val[1] - mu) * rs * gv.y + ev.y + xv.y;
  o4.z = (val[2] - mu) * rs * gv.z + ev.z + xv.z;
  o4.w = (val[3] - mu) * rs * gv.w + ev.w + xv.w;
  *(float4*)(out + (size_t)v * HC2 + c0) = o4;
}

// ---------------------------------------------------------------------------
extern "C" void kernel_launch(void* const* d_in, const int* in_sizes, int n_in,
                              void* d_out, int out_size, void* d_ws, size_t ws_size,
                              hipStream_t stream) {
  const float* x     = (const float*)d_in[0];
  const int*   ei    = (const int*)d_in[1];
  const float* eattr = (const float*)d_in[2];
  const float* Wl1   = (const float*)d_in[3];
  const float* Wr1   = (const float*)d_in[4];
  const float* We1   = (const float*)d_in[5];
  const float* att1  = (const float*)d_in[6];
  const float* b1    = (const float*)d_in[7];
  const float* g1    = (const float*)d_in[8];
  const float* be1   = (const float*)d_in[9];
  const float* Wl2   = (const float*)d_in[10];
  const float* Wr2   = (const float*)d_in[11];
  const float* We2   = (const float*)d_in[12];
  const float* att2  = (const float*)d_in[13];
  const float* b2    = (const float*)d_in[14];
  const float* g2    = (const float*)d_in[15];
  const float* be2   = (const float*)d_in[16];

  const int N    = in_sizes[0] / D_IN;   // 10000
  const int E    = in_sizes[2] / 4;      // 320000
  const int Etot = E + N;

  char* w = (char*)d_ws;
  auto alloc = [&](size_t bytes) -> void* {
    void* p = (void*)w;
    w += (bytes + 255) & ~(size_t)255;
    return p;
  };
  bf16*   xb    = (bf16*)alloc((size_t)N * D_IN * 2);
  bf16*   W1T   = (bf16*)alloc((size_t)1024 * 256 * 2);
  bf16*   W2T   = (bf16*)alloc((size_t)512 * 512 * 2);
  bf16*   xlr1  = (bf16*)alloc((size_t)N * 1024 * 2);
  bf16*   h1    = (bf16*)alloc((size_t)N * HC1 * 2);
  bf16*   xlr2  = (bf16*)alloc((size_t)N * 512 * 2);
  int*    srcs  = (int*)alloc((size_t)Etot * 4);
  float4* eaC   = (float4*)alloc((size_t)Etot * 16);
  int*    offs  = (int*)alloc((size_t)(N + 1) * 4);
  float*  mean4 = (float*)alloc(64);
  char*   zb    = w;
  int*    counts = (int*)alloc((size_t)N * 4);
  int*    cursor = (int*)alloc((size_t)N * 4);
  float*  sums   = (float*)alloc(64);
  size_t  zbytes = (size_t)(w - zb);

  hipMemsetAsync(zb, 0, zbytes, stream);

  int n4 = N * D_IN / 4;
  convx_kernel<<<(n4 + 255) / 256, 256, 0, stream>>>(x, xb, n4);
  transw_kernel<<<dim3(16, 16, 4), 256, 0, stream>>>(Wl1, Wr1, Wl2, Wr2, W1T, W2T);

  mean_kernel<<<256, 256, 0, stream>>>(eattr, sums, E);
  meanw_kernel<<<1, 64, 0, stream>>>(sums, mean4, 1.f / (float)E);

  count_kernel<<<1024, 256, 0, stream>>>(ei, counts, E, Etot);
  scan_kernel<<<1, 1024, 0, stream>>>(counts, offs, N);
  fill_kernel<<<1024, 256, 0, stream>>>(ei, offs, cursor, eattr, mean4, srcs, eaC, E, Etot);

  dim3 gg1(1024 / 128, (N + 127) / 128);
  gemm_mfma_kernel<<<gg1, 256, 0, stream>>>(xb, W1T, xlr1, N, 256, 1024);

  fused1_kernel<<<(N + 3) / 4, 256, 0, stream>>>(srcs, eaC, offs, xlr1, We1, att1,
                                                 b1, g1, be1, h1, N);

  dim3 gg2(512 / 128, (N + 127) / 128);
  gemm_mfma_kernel<<<gg2, 256, 0, stream>>>(h1, W2T, xlr2, N, 512, 512);

  fused2_kernel<<<(N + 3) / 4, 256, 0, stream>>>(srcs, eaC, offs, xlr2, We2, att2,
                                                 b2, g2, be2, x, (float*)d_out, N);
}

// Round 6
// 327.022 us; speedup vs baseline: 3.3662x; 1.0469x over previous
//
#include <hip/hip_runtime.h>
#include <hip/hip_bf16.h>

#define HC1 512   // layer-1 heads*channels (4*128)
#define HC2 256   // layer-2 (1*256)
#define D_IN 256

typedef __hip_bfloat16  bf16;
typedef __hip_bfloat162 bf162;
typedef __attribute__((ext_vector_type(8))) short short8;   // 8 bf16 = 4 VGPR
typedef __attribute__((ext_vector_type(4))) float f32x4;

__device__ __forceinline__ void unpack8(short8 q, float* x) {
  union { short8 s; bf162 h[4]; } u; u.s = q;
#pragma unroll
  for (int j = 0; j < 4; j++) {
    x[2 * j]     = __bfloat162float(u.h[j].x);
    x[2 * j + 1] = __bfloat162float(u.h[j].y);
  }
}

// ------------------------- async global->LDS (16B/lane) --------------------
__device__ __forceinline__ void glds16(const bf16* g, bf16* l) {
#if __has_builtin(__builtin_amdgcn_global_load_lds)
  __builtin_amdgcn_global_load_lds(
      (const __attribute__((address_space(1))) void*)g,
      (__attribute__((address_space(3))) void*)l, 16, 0, 0);
#else
  int lane = threadIdx.x & 63;
  ((int4*)l)[lane] = *(const int4*)g;
#endif
}

// ------------------------- bf16 MFMA GEMM ----------------------------------
// C[M,N] = A[M,K] @ BT[N,K]^T. Tile 128x128, BK=32, 4 waves, 64x64 each.
__global__ __launch_bounds__(256)
void gemm_mfma_kernel(const bf16* __restrict__ A, const bf16* __restrict__ BT,
                      bf16* __restrict__ C, int M, int K, int N) {
  __shared__ bf16 lds[8192];           // 16 KiB: A [0,4096), B [4096,8192)
  const int t = threadIdx.x;
  const int w  = t >> 6, l = t & 63;
  const int wr = w >> 1, wc = w & 1;
  const int lo = l & 15, hi = l >> 4;
  const int m0 = blockIdx.y * 128;
  const int n0 = blockIdx.x * 128;

  f32x4 acc[4][4] = {};

  const int c0 = w * 2, c1 = w * 2 + 1;
  const int kc0 = c0 >> 1, r0 = (c0 & 1) * 64 + l;
  const int kc1 = c1 >> 1, r1 = (c1 & 1) * 64 + l;
  int mr0 = m0 + r0; if (mr0 >= M) mr0 = M - 1;
  int mr1 = m0 + r1; if (mr1 >= M) mr1 = M - 1;
  const bf16* ga0 = A + (size_t)mr0 * K + kc0 * 8;
  const bf16* ga1 = A + (size_t)mr1 * K + kc1 * 8;
  const bf16* gb0 = BT + (size_t)(n0 + r0) * K + kc0 * 8;
  const bf16* gb1 = BT + (size_t)(n0 + r1) * K + kc1 * 8;
  bf16* la0 = &lds[c0 * 512];
  bf16* la1 = &lds[c1 * 512];
  bf16* lb0 = &lds[4096 + c0 * 512];
  bf16* lb1 = &lds[4096 + c1 * 512];

  for (int k0 = 0; k0 < K; k0 += 32) {
    if (k0) __syncthreads();
    glds16(ga0 + k0, la0);
    glds16(ga1 + k0, la1);
    glds16(gb0 + k0, lb0);
    glds16(gb1 + k0, lb1);
    __syncthreads();

    short8 af[4], bfr[4];
#pragma unroll
    for (int f = 0; f < 4; f++) {
      af[f]  = *(const short8*)&lds[hi * 1024 + (wr * 64 + f * 16 + lo) * 8];
      bfr[f] = *(const short8*)&lds[4096 + hi * 1024 + (wc * 64 + f * 16 + lo) * 8];
    }
#pragma unroll
    for (int fm = 0; fm < 4; fm++)
#pragma unroll
      for (int fn = 0; fn < 4; fn++)
        acc[fm][fn] = __builtin_amdgcn_mfma_f32_16x16x32_bf16(af[fm], bfr[fn],
                                                              acc[fm][fn], 0, 0, 0);
  }

#pragma unroll
  for (int fm = 0; fm < 4; fm++) {
#pragma unroll
    for (int r = 0; r < 4; r++) {
      int row = m0 + wr * 64 + fm * 16 + hi * 4 + r;
      if (row < M) {
#pragma unroll
        for (int fn = 0; fn < 4; fn++) {
          int col = n0 + wc * 64 + fn * 16 + lo;
          C[(size_t)row * N + col] = __float2bfloat16(acc[fm][fn][r]);
        }
      }
    }
  }
}

// ------------------------- prep: x -> bf16 ---------------------------------
__global__ void convx_kernel(const float* __restrict__ x, bf16* __restrict__ xb, int n4) {
  int i = blockIdx.x * blockDim.x + threadIdx.x;
  if (i >= n4) return;
  float4 v = ((const float4*)x)[i];
  union { bf16 h[4]; uint2 u; } cv;
  cv.h[0] = __float2bfloat16(v.x); cv.h[1] = __float2bfloat16(v.y);
  cv.h[2] = __float2bfloat16(v.z); cv.h[3] = __float2bfloat16(v.w);
  ((uint2*)xb)[i] = cv.u;
}

// tiled LDS transpose: out[n][k] = bf16(in[k][n]); 4 jobs via blockIdx.z
__global__ __launch_bounds__(256)
void transw_kernel(const float* __restrict__ Wl1, const float* __restrict__ Wr1,
                   const float* __restrict__ Wl2, const float* __restrict__ Wr2,
                   bf16* __restrict__ W1T, bf16* __restrict__ W2T) {
  __shared__ float tile[32][33];
  const int z = blockIdx.z;
  const float* in; bf16* out; int K, Nn;
  if (z == 0)      { in = Wl1; out = W1T;             K = 256; Nn = 512; }
  else if (z == 1) { in = Wr1; out = W1T + 512 * 256; K = 256; Nn = 512; }
  else if (z == 2) { in = Wl2; out = W2T;             K = 512; Nn = 256; }
  else             { in = Wr2; out = W2T + 256 * 512; K = 512; Nn = 256; }
  const int nt = blockIdx.x * 32, kt = blockIdx.y * 32;
  if (nt >= Nn || kt >= K) return;
  const int tx = threadIdx.x & 31, ty = threadIdx.x >> 5;
#pragma unroll
  for (int j = 0; j < 4; j++)
    tile[ty + j * 8][tx] = in[(size_t)(kt + ty + j * 8) * Nn + nt + tx];
  __syncthreads();
#pragma unroll
  for (int j = 0; j < 4; j++)
    out[(size_t)(nt + ty + j * 8) * K + kt + tx] = __float2bfloat16(tile[tx][ty + j * 8]);
}

// ------------------------- edge-attr mean ----------------------------------
__global__ void mean_kernel(const float* __restrict__ eattr, float* __restrict__ sums, int E) {
  int tid = blockIdx.x * blockDim.x + threadIdx.x;
  int stride = gridDim.x * blockDim.x;
  float l0 = 0.f, l1 = 0.f, l2 = 0.f, l3 = 0.f;
  for (int e = tid; e < E; e += stride) {
    float4 v = ((const float4*)eattr)[e];
    l0 += v.x; l1 += v.y; l2 += v.z; l3 += v.w;
  }
#pragma unroll
  for (int o = 1; o < 64; o <<= 1) {
    l0 += __shfl_xor(l0, o); l1 += __shfl_xor(l1, o);
    l2 += __shfl_xor(l2, o); l3 += __shfl_xor(l3, o);
  }
  if ((threadIdx.x & 63) == 0) {
    atomicAdd(&sums[0], l0); atomicAdd(&sums[1], l1);
    atomicAdd(&sums[2], l2); atomicAdd(&sums[3], l3);
  }
}

__global__ void meanw_kernel(const float* __restrict__ sums, float* __restrict__ mean4, float invE) {
  int t = threadIdx.x;
  if (t < 4) mean4[t] = sums[t] * invE;
}

// ------------------------- CSR build ---------------------------------------
__global__ void count_kernel(const int* __restrict__ ei, int* __restrict__ counts, int E, int Etot) {
  int tid = blockIdx.x * blockDim.x + threadIdx.x;
  int stride = gridDim.x * blockDim.x;
  for (int e = tid; e < Etot; e += stride) {
    int dst = (e < E) ? ei[E + e] : (e - E);
    atomicAdd(&counts[dst], 1);
  }
}

__global__ __launch_bounds__(1024)
void scan_kernel(const int* __restrict__ counts, int* __restrict__ offs, int N) {
  __shared__ int wsum[16];
  int tid = threadIdx.x, wid = tid >> 6, lane = tid & 63;
  if (tid == 0) offs[0] = 0;
  int carry = 0;
  for (int base = 0; base < N; base += 1024) {
    int i = base + tid;
    int v = (i < N) ? counts[i] : 0;
    int s = v;
#pragma unroll
    for (int o = 1; o < 64; o <<= 1) {
      int u = __shfl_up(s, o);
      if (lane >= o) s += u;
    }
    if (lane == 63) wsum[wid] = s;
    __syncthreads();
    if (wid == 0) {
      int t2 = (lane < 16) ? wsum[lane] : 0;
#pragma unroll
      for (int o = 1; o < 16; o <<= 1) {
        int u = __shfl_up(t2, o);
        if (lane >= o) t2 += u;
      }
      if (lane < 16) wsum[lane] = t2;
    }
    __syncthreads();
    int pre = (wid > 0) ? wsum[wid - 1] : 0;
    int tot = wsum[15];
    if (i < N) offs[i + 1] = carry + pre + s;
    carry += tot;
    __syncthreads();
  }
}

__global__ void fill_kernel(const int* __restrict__ ei, const int* __restrict__ offs,
                            int* __restrict__ cursor, const float* __restrict__ eattr,
                            const float* __restrict__ mean4, int* __restrict__ srcs,
                            float4* __restrict__ eaC, int E, int Etot) {
  int tid = blockIdx.x * blockDim.x + threadIdx.x;
  int stride = gridDim.x * blockDim.x;
  for (int e = tid; e < Etot; e += stride) {
    int src, dst;
    if (e < E) { src = ei[e]; dst = ei[E + e]; } else { src = e - E; dst = src; }
    int pos = atomicAdd(&cursor[dst], 1);
    int slot = offs[dst] + pos;
    srcs[slot] = src;
    eaC[slot] = (e < E) ? ((const float4*)eattr)[e] : *(const float4*)mean4;
  }
}

// ---------------- layer 1 fused: one BLOCK per node, 4 waves split edges ---
// xlr: [N][1024] bf16 = [xl(512) | xr(512)]; lane covers 8 ch, head = lane>>4.
// NOTE: den is PER-HEAD (score reduce spans 16-lane groups) -> dens[wave][head].
__global__ __launch_bounds__(256)
void fused1_kernel(const int* __restrict__ srcs, const float4* __restrict__ eaC,
                   const int* __restrict__ offs, const bf16* __restrict__ xlr,
                   const float* __restrict__ We, const float* __restrict__ att,
                   const float* __restrict__ bias, const float* __restrict__ g,
                   const float* __restrict__ be, bf16* __restrict__ h1) {
  const int v = blockIdx.x;
  const int tid = threadIdx.x;
  const int wave = tid >> 6, lane = tid & 63;
  const int ch = lane * 8;

  float w0[8], w1[8], w2[8], w3[8], aw[8], xr[8];
  *(float4*)&w0[0] = *(const float4*)(We + 0 * HC1 + ch);
  *(float4*)&w0[4] = *(const float4*)(We + 0 * HC1 + ch + 4);
  *(float4*)&w1[0] = *(const float4*)(We + 1 * HC1 + ch);
  *(float4*)&w1[4] = *(const float4*)(We + 1 * HC1 + ch + 4);
  *(float4*)&w2[0] = *(const float4*)(We + 2 * HC1 + ch);
  *(float4*)&w2[4] = *(const float4*)(We + 2 * HC1 + ch + 4);
  *(float4*)&w3[0] = *(const float4*)(We + 3 * HC1 + ch);
  *(float4*)&w3[4] = *(const float4*)(We + 3 * HC1 + ch + 4);
  *(float4*)&aw[0] = *(const float4*)(att + ch);
  *(float4*)&aw[4] = *(const float4*)(att + ch + 4);
  unpack8(*(const short8*)(xlr + (size_t)v * 1024 + 512 + ch), xr);

  const int beg = offs[v], end = offs[v + 1];
  float den = 0.f;
  float acc[8] = {};

  // wave w handles edges beg+w, beg+w+4, beg+w+8, ... (2 per iteration)
  for (int i = beg + wave; i < end; i += 8) {
    const int i2 = i + 4;
    const bool two = (i2 < end);
    int s0 = srcs[i];
    int s1 = two ? srcs[i2] : s0;
    float4 e0 = eaC[i];
    float4 e1 = two ? eaC[i2] : e0;
    short8 q0 = *(const short8*)(xlr + (size_t)s0 * 1024 + ch);
    short8 q1 = *(const short8*)(xlr + (size_t)s1 * 1024 + ch);
    {
      float xa[8]; unpack8(q0, xa);
      float p = 0.f;
#pragma unroll
      for (int j = 0; j < 8; j++) {
        float m = xa[j] + xr[j];
        m = fmaf(e0.x, w0[j], m); m = fmaf(e0.y, w1[j], m);
        m = fmaf(e0.z, w2[j], m); m = fmaf(e0.w, w3[j], m);
        p = fmaf(fmaxf(m, 0.2f * m), aw[j], p);
      }
      p += __shfl_xor(p, 1); p += __shfl_xor(p, 2);
      p += __shfl_xor(p, 4); p += __shfl_xor(p, 8);
      float ex = __expf(p);
      den += ex;
#pragma unroll
      for (int j = 0; j < 8; j++) acc[j] = fmaf(ex, xa[j], acc[j]);
    }
    if (two) {
      float xa[8]; unpack8(q1, xa);
      float p = 0.f;
#pragma unroll
      for (int j = 0; j < 8; j++) {
        float m = xa[j] + xr[j];
        m = fmaf(e1.x, w0[j], m); m = fmaf(e1.y, w1[j], m);
        m = fmaf(e1.z, w2[j], m); m = fmaf(e1.w, w3[j], m);
        p = fmaf(fmaxf(m, 0.2f * m), aw[j], p);
      }
      p += __shfl_xor(p, 1); p += __shfl_xor(p, 2);
      p += __shfl_xor(p, 4); p += __shfl_xor(p, 8);
      float ex = __expf(p);
      den += ex;
#pragma unroll
      for (int j = 0; j < 8; j++) acc[j] = fmaf(ex, xa[j], acc[j]);
    }
  }

  // ----- cross-wave combine -----
  __shared__ float accs[4][HC1];
  __shared__ float dens[4][4];     // [wave][head]
  __shared__ float2 red[4];
  *(float4*)&accs[wave][ch]     = *(float4*)&acc[0];
  *(float4*)&accs[wave][ch + 4] = *(float4*)&acc[4];
  if ((lane & 15) == 0) dens[wave][lane >> 4] = den;   // per-head partial
  __syncthreads();

  const int c = tid * 2;          // each thread: 2 channels for epilogue
  const int head = c >> 7;        // 128 channels per head
  const float dtot = dens[0][head] + dens[1][head] + dens[2][head] + dens[3][head];
  const float rden = 1.f / (dtot + 1e-16f);
  float2 a0 = *(float2*)&accs[0][c];
  float2 a1 = *(float2*)&accs[1][c];
  float2 a2 = *(float2*)&accs[2][c];
  float2 a3 = *(float2*)&accs[3][c];
  float2 bv = *(const float2*)(bias + c);
  float val0 = (a0.x + a1.x + a2.x + a3.x) * rden + bv.x;
  float val1 = (a0.y + a1.y + a2.y + a3.y) * rden + bv.y;

  float s1 = val0 + val1, s2 = val0 * val0 + val1 * val1;
#pragma unroll
  for (int o = 1; o < 64; o <<= 1) { s1 += __shfl_xor(s1, o); s2 += __shfl_xor(s2, o); }
  if (lane == 0) red[wave] = make_float2(s1, s2);
  __syncthreads();
  float ts1 = red[0].x + red[1].x + red[2].x + red[3].x;
  float ts2 = red[0].y + red[1].y + red[2].y + red[3].y;
  float mu  = ts1 * (1.f / HC1);
  float var = ts2 * (1.f / HC1) - mu * mu;
  float rs  = rsqrtf(var + 1e-5f);

  float2 gv = *(const float2*)(g + c);
  float2 ev = *(const float2*)(be + c);
  float ya = (val0 - mu) * rs * gv.x + ev.x;
  float yb = (val1 - mu) * rs * gv.y + ev.y;
  ya = (ya > 0.f) ? ya : expm1f(ya);
  yb = (yb > 0.f) ? yb : expm1f(yb);
  bf162 hv;
  hv.x = __float2bfloat16(ya); hv.y = __float2bfloat16(yb);
  *(bf162*)(h1 + (size_t)v * HC1 + c) = hv;
}

// ---------------- layer 2 fused: one BLOCK per node, 4 waves split edges ---
// xlr: [N][512] bf16 = [xl(256) | xr(256)]; lane covers 4 ch.
// (den uniform across wave here: score reduce spans all 64 lanes)
__global__ __launch_bounds__(256)
void fused2_kernel(const int* __restrict__ srcs, const float4* __restrict__ eaC,
                   const int* __restrict__ offs, const bf16* __restrict__ xlr,
                   const float* __restrict__ We, const float* __restrict__ att,
                   const float* __restrict__ bias, const float* __restrict__ g,
                   const float* __restrict__ be, const float* __restrict__ xin,
                   float* __restrict__ out) {
  const int v = blockIdx.x;
  const int tid = threadIdx.x;
  const int wave = tid >> 6, lane = tid & 63;
  const int c0 = lane * 4;

  float w[4][4];
#pragma unroll
  for (int k = 0; k < 4; k++) {
    float4 q = *(const float4*)(We + k * HC2 + c0);
    w[k][0] = q.x; w[k][1] = q.y; w[k][2] = q.z; w[k][3] = q.w;
  }
  float4 atv = *(const float4*)(att + c0);
  float at[4] = {atv.x, atv.y, atv.z, atv.w};
  float xrv[4];
  {
    union { short4 s; bf162 h[2]; } u;
    u.s = *(const short4*)(xlr + (size_t)v * 512 + 256 + c0);
    xrv[0] = __bfloat162float(u.h[0].x); xrv[1] = __bfloat162float(u.h[0].y);
    xrv[2] = __bfloat162float(u.h[1].x); xrv[3] = __bfloat162float(u.h[1].y);
  }

  const int beg = offs[v], end = offs[v + 1];
  float den = 0.f, acc[4] = {0.f, 0.f, 0.f, 0.f};

  for (int i = beg + wave; i < end; i += 8) {
    const int i2 = i + 4;
    const bool two = (i2 < end);
    int s0 = srcs[i];
    int s1 = two ? srcs[i2] : s0;
    float4 e0 = eaC[i];
    float4 e1 = two ? eaC[i2] : e0;
    union { short4 s; bf162 h[2]; } ua, ub;
    ua.s = *(const short4*)(xlr + (size_t)s0 * 512 + c0);
    ub.s = *(const short4*)(xlr + (size_t)s1 * 512 + c0);
    {
      float xa[4] = {__bfloat162float(ua.h[0].x), __bfloat162float(ua.h[0].y),
                     __bfloat162float(ua.h[1].x), __bfloat162float(ua.h[1].y)};
      float p = 0.f;
#pragma unroll
      for (int j = 0; j < 4; j++) {
        float m = xa[j] + xrv[j];
        m = fmaf(e0.x, w[0][j], m); m = fmaf(e0.y, w[1][j], m);
        m = fmaf(e0.z, w[2][j], m); m = fmaf(e0.w, w[3][j], m);
        p = fmaf(fmaxf(m, 0.2f * m), at[j], p);
      }
#pragma unroll
      for (int o = 1; o < 64; o <<= 1) p += __shfl_xor(p, o);
      float ex = __expf(p);
      den += ex;
#pragma unroll
      for (int j = 0; j < 4; j++) acc[j] = fmaf(ex, xa[j], acc[j]);
    }
    if (two) {
      float xa[4] = {__bfloat162float(ub.h[0].x), __bfloat162float(ub.h[0].y),
                     __bfloat162float(ub.h[1].x), __bfloat162float(ub.h[1].y)};
      float p = 0.f;
#pragma unroll
      for (int j = 0; j < 4; j++) {
        float m = xa[j] + xrv[j];
        m = fmaf(e1.x, w[0][j], m); m = fmaf(e1.y, w[1][j], m);
        m = fmaf(e1.z, w[2][j], m); m = fmaf(e1.w, w[3][j], m);
        p = fmaf(fmaxf(m, 0.2f * m), at[j], p);
      }
#pragma unroll
      for (int o = 1; o < 64; o <<= 1) p += __shfl_xor(p, o);
      float ex = __expf(p);
      den += ex;
#pragma unroll
      for (int j = 0; j < 4; j++) acc[j] = fmaf(ex, xa[j], acc[j]);
    }
  }

  // ----- cross-wave combine -----
  __shared__ float accs[4][HC2];
  __shared__ float dens[4];
  __shared__ float2 red[4];
  *(float4*)&accs[wave][c0] = *(float4*)&acc[0];
  if (lane == 0) dens[wave] = den;
  __syncthreads();

  const int c = tid;              // each thread: 1 channel
  const float dtot = dens[0] + dens[1] + dens[2] + dens[3];
  const float rden = 1.f / (dtot + 1e-16f);
  float val = (accs[0][c] + accs[1][c] + accs[2][c] + accs[3][c]) * rden + bias[c];

  float s1 = val, s2 = val * val;
#pragma unroll
  for (int o = 1; o < 64; o <<= 1) { s1 += __shfl_xor(s1, o); s2 += __shfl_xor(s2, o); }
  if (lane == 0) red[wave] = make_float2(s1, s2);
  __syncthreads();
  float ts1 = red[0].x + red[1].x + red[2].x + red[3].x;
  float ts2 = red[0].y + red[1].y + red[2].y + red[3].y;
  float mu  = ts1 * (1.f / HC2);
  float var = ts2 * (1.f / HC2) - mu * mu;
  float rs  = rsqrtf(var + 1e-5f);
  float y = (val - mu) * rs * g[c] + be[c];
  out[(size_t)v * HC2 + c] = y + xin[(size_t)v * HC2 + c];
}

// ---------------------------------------------------------------------------
extern "C" void kernel_launch(void* const* d_in, const int* in_sizes, int n_in,
                              void* d_out, int out_size, void* d_ws, size_t ws_size,
                              hipStream_t stream) {
  const float* x     = (const float*)d_in[0];
  const int*   ei    = (const int*)d_in[1];
  const float* eattr = (const float*)d_in[2];
  const float* Wl1   = (const float*)d_in[3];
  const float* Wr1   = (const float*)d_in[4];
  const float* We1   = (const float*)d_in[5];
  const float* att1  = (const float*)d_in[6];
  const float* b1    = (const float*)d_in[7];
  const float* g1    = (const float*)d_in[8];
  const float* be1   = (const float*)d_in[9];
  const float* Wl2   = (const float*)d_in[10];
  const float* Wr2   = (const float*)d_in[11];
  const float* We2   = (const float*)d_in[12];
  const float* att2  = (const float*)d_in[13];
  const float* b2    = (const float*)d_in[14];
  const float* g2    = (const float*)d_in[15];
  const float* be2   = (const float*)d_in[16];

  const int N    = in_sizes[0] / D_IN;   // 10000
  const int E    = in_sizes[2] / 4;      // 320000
  const int Etot = E + N;

  char* w = (char*)d_ws;
  auto alloc = [&](size_t bytes) -> void* {
    void* p = (void*)w;
    w += (bytes + 255) & ~(size_t)255;
    return p;
  };
  bf16*   xb    = (bf16*)alloc((size_t)N * D_IN * 2);
  bf16*   W1T   = (bf16*)alloc((size_t)1024 * 256 * 2);
  bf16*   W2T   = (bf16*)alloc((size_t)512 * 512 * 2);
  bf16*   xlr1  = (bf16*)alloc((size_t)N * 1024 * 2);
  bf16*   h1    = (bf16*)alloc((size_t)N * HC1 * 2);
  bf16*   xlr2  = (bf16*)alloc((size_t)N * 512 * 2);
  int*    srcs  = (int*)alloc((size_t)Etot * 4);
  float4* eaC   = (float4*)alloc((size_t)Etot * 16);
  int*    offs  = (int*)alloc((size_t)(N + 1) * 4);
  float*  mean4 = (float*)alloc(64);
  char*   zb    = w;
  int*    counts = (int*)alloc((size_t)N * 4);
  int*    cursor = (int*)alloc((size_t)N * 4);
  float*  sums   = (float*)alloc(64);
  size_t  zbytes = (size_t)(w - zb);

  hipMemsetAsync(zb, 0, zbytes, stream);

  int n4 = N * D_IN / 4;
  convx_kernel<<<(n4 + 255) / 256, 256, 0, stream>>>(x, xb, n4);
  transw_kernel<<<dim3(16, 16, 4), 256, 0, stream>>>(Wl1, Wr1, Wl2, Wr2, W1T, W2T);

  mean_kernel<<<256, 256, 0, stream>>>(eattr, sums, E);
  meanw_kernel<<<1, 64, 0, stream>>>(sums, mean4, 1.f / (float)E);

  count_kernel<<<1024, 256, 0, stream>>>(ei, counts, E, Etot);
  scan_kernel<<<1, 1024, 0, stream>>>(counts, offs, N);
  fill_kernel<<<1024, 256, 0, stream>>>(ei, offs, cursor, eattr, mean4, srcs, eaC, E, Etot);

  dim3 gg1(1024 / 128, (N + 127) / 128);
  gemm_mfma_kernel<<<gg1, 256, 0, stream>>>(xb, W1T, xlr1, N, 256, 1024);

  fused1_kernel<<<N, 256, 0, stream>>>(srcs, eaC, offs, xlr1, We1, att1, b1, g1, be1, h1);

  dim3 gg2(512 / 128, (N + 127) / 128);
  gemm_mfma_kernel<<<gg2, 256, 0, stream>>>(h1, W2T, xlr2, N, 512, 512);

  fused2_kernel<<<N, 256, 0, stream>>>(srcs, eaC, offs, xlr2, We2, att2,
                                       b2, g2, be2, x, (float*)d_out);
}

// Round 7
// 292.445 us; speedup vs baseline: 3.7642x; 1.1182x over previous
//
#include <hip/hip_runtime.h>
#include <hip/hip_bf16.h>

#define HC1 512   // layer-1 heads*channels (4*128)
#define HC2 256   // layer-2 (1*256)
#define D_IN 256

typedef __hip_bfloat16  bf16;
typedef __hip_bfloat162 bf162;
typedef __attribute__((ext_vector_type(8))) short short8;   // 8 bf16 = 4 VGPR
typedef __attribute__((ext_vector_type(4))) float f32x4;

__device__ __forceinline__ void unpack8(short8 q, float* x) {
  union { short8 s; bf162 h[4]; } u; u.s = q;
#pragma unroll
  for (int j = 0; j < 4; j++) {
    x[2 * j]     = __bfloat162float(u.h[j].x);
    x[2 * j + 1] = __bfloat162float(u.h[j].y);
  }
}

// ------------------------- async global->LDS (16B/lane) --------------------
__device__ __forceinline__ void glds16(const bf16* g, bf16* l) {
#if __has_builtin(__builtin_amdgcn_global_load_lds)
  __builtin_amdgcn_global_load_lds(
      (const __attribute__((address_space(1))) void*)g,
      (__attribute__((address_space(3))) void*)l, 16, 0, 0);
#else
  int lane = threadIdx.x & 63;
  ((int4*)l)[lane] = *(const int4*)g;
#endif
}

// ------------------------- bf16 MFMA GEMM ----------------------------------
// C[M,N] = A[M,K] @ BT[N,K]^T. Tile 128x128, BK=32, 4 waves, 64x64 each.
__global__ __launch_bounds__(256)
void gemm_mfma_kernel(const bf16* __restrict__ A, const bf16* __restrict__ BT,
                      bf16* __restrict__ C, int M, int K, int N) {
  __shared__ bf16 lds[8192];           // 16 KiB: A [0,4096), B [4096,8192)
  const int t = threadIdx.x;
  const int w  = t >> 6, l = t & 63;
  const int wr = w >> 1, wc = w & 1;
  const int lo = l & 15, hi = l >> 4;
  const int m0 = blockIdx.y * 128;
  const int n0 = blockIdx.x * 128;

  f32x4 acc[4][4] = {};

  const int c0 = w * 2, c1 = w * 2 + 1;
  const int kc0 = c0 >> 1, r0 = (c0 & 1) * 64 + l;
  const int kc1 = c1 >> 1, r1 = (c1 & 1) * 64 + l;
  int mr0 = m0 + r0; if (mr0 >= M) mr0 = M - 1;
  int mr1 = m0 + r1; if (mr1 >= M) mr1 = M - 1;
  const bf16* ga0 = A + (size_t)mr0 * K + kc0 * 8;
  const bf16* ga1 = A + (size_t)mr1 * K + kc1 * 8;
  const bf16* gb0 = BT + (size_t)(n0 + r0) * K + kc0 * 8;
  const bf16* gb1 = BT + (size_t)(n0 + r1) * K + kc1 * 8;
  bf16* la0 = &lds[c0 * 512];
  bf16* la1 = &lds[c1 * 512];
  bf16* lb0 = &lds[4096 + c0 * 512];
  bf16* lb1 = &lds[4096 + c1 * 512];

  for (int k0 = 0; k0 < K; k0 += 32) {
    if (k0) __syncthreads();
    glds16(ga0 + k0, la0);
    glds16(ga1 + k0, la1);
    glds16(gb0 + k0, lb0);
    glds16(gb1 + k0, lb1);
    __syncthreads();

    short8 af[4], bfr[4];
#pragma unroll
    for (int f = 0; f < 4; f++) {
      af[f]  = *(const short8*)&lds[hi * 1024 + (wr * 64 + f * 16 + lo) * 8];
      bfr[f] = *(const short8*)&lds[4096 + hi * 1024 + (wc * 64 + f * 16 + lo) * 8];
    }
#pragma unroll
    for (int fm = 0; fm < 4; fm++)
#pragma unroll
      for (int fn = 0; fn < 4; fn++)
        acc[fm][fn] = __builtin_amdgcn_mfma_f32_16x16x32_bf16(af[fm], bfr[fn],
                                                              acc[fm][fn], 0, 0, 0);
  }

#pragma unroll
  for (int fm = 0; fm < 4; fm++) {
#pragma unroll
    for (int r = 0; r < 4; r++) {
      int row = m0 + wr * 64 + fm * 16 + hi * 4 + r;
      if (row < M) {
#pragma unroll
        for (int fn = 0; fn < 4; fn++) {
          int col = n0 + wc * 64 + fn * 16 + lo;
          C[(size_t)row * N + col] = __float2bfloat16(acc[fm][fn][r]);
        }
      }
    }
  }
}

// ------------------------- prep: x -> bf16 ---------------------------------
__global__ void convx_kernel(const float* __restrict__ x, bf16* __restrict__ xb, int n4) {
  int i = blockIdx.x * blockDim.x + threadIdx.x;
  if (i >= n4) return;
  float4 v = ((const float4*)x)[i];
  union { bf16 h[4]; uint2 u; } cv;
  cv.h[0] = __float2bfloat16(v.x); cv.h[1] = __float2bfloat16(v.y);
  cv.h[2] = __float2bfloat16(v.z); cv.h[3] = __float2bfloat16(v.w);
  ((uint2*)xb)[i] = cv.u;
}

// tiled LDS transpose: out[n][k] = bf16(in[k][n]); 4 jobs via blockIdx.z
__global__ __launch_bounds__(256)
void transw_kernel(const float* __restrict__ Wl1, const float* __restrict__ Wr1,
                   const float* __restrict__ Wl2, const float* __restrict__ Wr2,
                   bf16* __restrict__ W1T, bf16* __restrict__ W2T) {
  __shared__ float tile[32][33];
  const int z = blockIdx.z;
  const float* in; bf16* out; int K, Nn;
  if (z == 0)      { in = Wl1; out = W1T;             K = 256; Nn = 512; }
  else if (z == 1) { in = Wr1; out = W1T + 512 * 256; K = 256; Nn = 512; }
  else if (z == 2) { in = Wl2; out = W2T;             K = 512; Nn = 256; }
  else             { in = Wr2; out = W2T + 256 * 512; K = 512; Nn = 256; }
  const int nt = blockIdx.x * 32, kt = blockIdx.y * 32;
  if (nt >= Nn || kt >= K) return;
  const int tx = threadIdx.x & 31, ty = threadIdx.x >> 5;
#pragma unroll
  for (int j = 0; j < 4; j++)
    tile[ty + j * 8][tx] = in[(size_t)(kt + ty + j * 8) * Nn + nt + tx];
  __syncthreads();
#pragma unroll
  for (int j = 0; j < 4; j++)
    out[(size_t)(nt + ty + j * 8) * K + kt + tx] = __float2bfloat16(tile[tx][ty + j * 8]);
}

// ------------------------- edge-attr mean ----------------------------------
__global__ void mean_kernel(const float* __restrict__ eattr, float* __restrict__ sums, int E) {
  int tid = blockIdx.x * blockDim.x + threadIdx.x;
  int stride = gridDim.x * blockDim.x;
  float l0 = 0.f, l1 = 0.f, l2 = 0.f, l3 = 0.f;
  for (int e = tid; e < E; e += stride) {
    float4 v = ((const float4*)eattr)[e];
    l0 += v.x; l1 += v.y; l2 += v.z; l3 += v.w;
  }
#pragma unroll
  for (int o = 1; o < 64; o <<= 1) {
    l0 += __shfl_xor(l0, o); l1 += __shfl_xor(l1, o);
    l2 += __shfl_xor(l2, o); l3 += __shfl_xor(l3, o);
  }
  if ((threadIdx.x & 63) == 0) {
    atomicAdd(&sums[0], l0); atomicAdd(&sums[1], l1);
    atomicAdd(&sums[2], l2); atomicAdd(&sums[3], l3);
  }
}

__global__ void meanw_kernel(const float* __restrict__ sums, float* __restrict__ mean4, float invE) {
  int t = threadIdx.x;
  if (t < 4) mean4[t] = sums[t] * invE;
}

// ------------------------- CSR build ---------------------------------------
__global__ void count_kernel(const int* __restrict__ ei, int* __restrict__ counts, int E, int Etot) {
  int tid = blockIdx.x * blockDim.x + threadIdx.x;
  int stride = gridDim.x * blockDim.x;
  for (int e = tid; e < Etot; e += stride) {
    int dst = (e < E) ? ei[E + e] : (e - E);
    atomicAdd(&counts[dst], 1);
  }
}

__global__ __launch_bounds__(1024)
void scan_kernel(const int* __restrict__ counts, int* __restrict__ offs, int N) {
  __shared__ int wsum[16];
  int tid = threadIdx.x, wid = tid >> 6, lane = tid & 63;
  if (tid == 0) offs[0] = 0;
  int carry = 0;
  for (int base = 0; base < N; base += 1024) {
    int i = base + tid;
    int v = (i < N) ? counts[i] : 0;
    int s = v;
#pragma unroll
    for (int o = 1; o < 64; o <<= 1) {
      int u = __shfl_up(s, o);
      if (lane >= o) s += u;
    }
    if (lane == 63) wsum[wid] = s;
    __syncthreads();
    if (wid == 0) {
      int t2 = (lane < 16) ? wsum[lane] : 0;
#pragma unroll
      for (int o = 1; o < 16; o <<= 1) {
        int u = __shfl_up(t2, o);
        if (lane >= o) t2 += u;
      }
      if (lane < 16) wsum[lane] = t2;
    }
    __syncthreads();
    int pre = (wid > 0) ? wsum[wid - 1] : 0;
    int tot = wsum[15];
    if (i < N) offs[i + 1] = carry + pre + s;
    carry += tot;
    __syncthreads();
  }
}

__global__ void fill_kernel(const int* __restrict__ ei, const int* __restrict__ offs,
                            int* __restrict__ cursor, const float* __restrict__ eattr,
                            const float* __restrict__ mean4, int* __restrict__ srcs,
                            float4* __restrict__ eaC, int E, int Etot) {
  int tid = blockIdx.x * blockDim.x + threadIdx.x;
  int stride = gridDim.x * blockDim.x;
  for (int e = tid; e < Etot; e += stride) {
    int src, dst;
    if (e < E) { src = ei[e]; dst = ei[E + e]; } else { src = e - E; dst = src; }
    int pos = atomicAdd(&cursor[dst], 1);
    int slot = offs[dst] + pos;
    srcs[slot] = src;
    eaC[slot] = (e < E) ? ((const float4*)eattr)[e] : *(const float4*)mean4;
  }
}

// ---------------- layer 1 fused: block/node, contiguous chunks, 4x unroll --
// xlr: [N][1024] bf16 = [xl(512) | xr(512)]; lane covers 8 ch, head = lane>>4.
__global__ __launch_bounds__(256, 4)
void fused1_kernel(const int* __restrict__ srcs, const float4* __restrict__ eaC,
                   const int* __restrict__ offs, const bf16* __restrict__ xlr,
                   const float* __restrict__ We, const float* __restrict__ att,
                   const float* __restrict__ bias, const float* __restrict__ g,
                   const float* __restrict__ be, bf16* __restrict__ h1) {
  const int v = blockIdx.x;
  const int tid = threadIdx.x;
  const int wave = tid >> 6, lane = tid & 63;
  const int ch = lane * 8;

  float w0[8], w1[8], w2[8], w3[8], aw[8], xr[8];
  *(float4*)&w0[0] = *(const float4*)(We + 0 * HC1 + ch);
  *(float4*)&w0[4] = *(const float4*)(We + 0 * HC1 + ch + 4);
  *(float4*)&w1[0] = *(const float4*)(We + 1 * HC1 + ch);
  *(float4*)&w1[4] = *(const float4*)(We + 1 * HC1 + ch + 4);
  *(float4*)&w2[0] = *(const float4*)(We + 2 * HC1 + ch);
  *(float4*)&w2[4] = *(const float4*)(We + 2 * HC1 + ch + 4);
  *(float4*)&w3[0] = *(const float4*)(We + 3 * HC1 + ch);
  *(float4*)&w3[4] = *(const float4*)(We + 3 * HC1 + ch + 4);
  *(float4*)&aw[0] = *(const float4*)(att + ch);
  *(float4*)&aw[4] = *(const float4*)(att + ch + 4);
  unpack8(*(const short8*)(xlr + (size_t)v * 1024 + 512 + ch), xr);

  const int beg = offs[v], end = offs[v + 1];
  const int len = end - beg;
  const int chunk = (len + 3) >> 2;       // contiguous quarter per wave
  int ib = beg + wave * chunk;
  int ie = ib + chunk;
  if (ib > end) ib = end;
  if (ie > end) ie = end;

  float den = 0.f;
  float acc[8] = {};

  auto edge = [&](short8 q, float4 e) {
    float xa[8]; unpack8(q, xa);
    float p = 0.f;
#pragma unroll
    for (int j = 0; j < 8; j++) {
      float m = xa[j] + xr[j];
      m = fmaf(e.x, w0[j], m); m = fmaf(e.y, w1[j], m);
      m = fmaf(e.z, w2[j], m); m = fmaf(e.w, w3[j], m);
      p = fmaf(fmaxf(m, 0.2f * m), aw[j], p);
    }
    p += __shfl_xor(p, 1); p += __shfl_xor(p, 2);
    p += __shfl_xor(p, 4); p += __shfl_xor(p, 8);
    float ex = __expf(p);
    den += ex;
#pragma unroll
    for (int j = 0; j < 8; j++) acc[j] = fmaf(ex, xa[j], acc[j]);
  };

  int i = ib;
  for (; i + 4 <= ie; i += 4) {
    int s0 = srcs[i], s1 = srcs[i + 1], s2 = srcs[i + 2], s3 = srcs[i + 3];
    float4 e0 = eaC[i], e1 = eaC[i + 1], e2 = eaC[i + 2], e3 = eaC[i + 3];
    short8 q0 = *(const short8*)(xlr + (size_t)s0 * 1024 + ch);
    short8 q1 = *(const short8*)(xlr + (size_t)s1 * 1024 + ch);
    short8 q2 = *(const short8*)(xlr + (size_t)s2 * 1024 + ch);
    short8 q3 = *(const short8*)(xlr + (size_t)s3 * 1024 + ch);
    edge(q0, e0); edge(q1, e1); edge(q2, e2); edge(q3, e3);
  }
  for (; i < ie; ++i) {
    int s0 = srcs[i];
    float4 e0 = eaC[i];
    short8 q0 = *(const short8*)(xlr + (size_t)s0 * 1024 + ch);
    edge(q0, e0);
  }

  // ----- cross-wave combine -----
  __shared__ float accs[4][HC1];
  __shared__ float dens[4][4];     // [wave][head]
  __shared__ float2 red[4];
  *(float4*)&accs[wave][ch]     = *(float4*)&acc[0];
  *(float4*)&accs[wave][ch + 4] = *(float4*)&acc[4];
  if ((lane & 15) == 0) dens[wave][lane >> 4] = den;   // per-head partial
  __syncthreads();

  const int c = tid * 2;          // each thread: 2 channels for epilogue
  const int head = c >> 7;        // 128 channels per head
  const float dtot = dens[0][head] + dens[1][head] + dens[2][head] + dens[3][head];
  const float rden = 1.f / (dtot + 1e-16f);
  float2 a0 = *(float2*)&accs[0][c];
  float2 a1 = *(float2*)&accs[1][c];
  float2 a2 = *(float2*)&accs[2][c];
  float2 a3 = *(float2*)&accs[3][c];
  float2 bv = *(const float2*)(bias + c);
  float val0 = (a0.x + a1.x + a2.x + a3.x) * rden + bv.x;
  float val1 = (a0.y + a1.y + a2.y + a3.y) * rden + bv.y;

  float s1 = val0 + val1, s2 = val0 * val0 + val1 * val1;
#pragma unroll
  for (int o = 1; o < 64; o <<= 1) { s1 += __shfl_xor(s1, o); s2 += __shfl_xor(s2, o); }
  if (lane == 0) red[wave] = make_float2(s1, s2);
  __syncthreads();
  float ts1 = red[0].x + red[1].x + red[2].x + red[3].x;
  float ts2 = red[0].y + red[1].y + red[2].y + red[3].y;
  float mu  = ts1 * (1.f / HC1);
  float var = ts2 * (1.f / HC1) - mu * mu;
  float rs  = rsqrtf(var + 1e-5f);

  float2 gv = *(const float2*)(g + c);
  float2 ev = *(const float2*)(be + c);
  float ya = (val0 - mu) * rs * gv.x + ev.x;
  float yb = (val1 - mu) * rs * gv.y + ev.y;
  ya = (ya > 0.f) ? ya : expm1f(ya);
  yb = (yb > 0.f) ? yb : expm1f(yb);
  bf162 hv;
  hv.x = __float2bfloat16(ya); hv.y = __float2bfloat16(yb);
  *(bf162*)(h1 + (size_t)v * HC1 + c) = hv;
}

// ---------------- layer 2 fused: block/node, contiguous chunks, 4x unroll --
// xlr: [N][512] bf16 = [xl(256) | xr(256)]; lane covers 4 ch.
__global__ __launch_bounds__(256, 4)
void fused2_kernel(const int* __restrict__ srcs, const float4* __restrict__ eaC,
                   const int* __restrict__ offs, const bf16* __restrict__ xlr,
                   const float* __restrict__ We, const float* __restrict__ att,
                   const float* __restrict__ bias, const float* __restrict__ g,
                   const float* __restrict__ be, const float* __restrict__ xin,
                   float* __restrict__ out) {
  const int v = blockIdx.x;
  const int tid = threadIdx.x;
  const int wave = tid >> 6, lane = tid & 63;
  const int c0 = lane * 4;

  float w[4][4];
#pragma unroll
  for (int k = 0; k < 4; k++) {
    float4 q = *(const float4*)(We + k * HC2 + c0);
    w[k][0] = q.x; w[k][1] = q.y; w[k][2] = q.z; w[k][3] = q.w;
  }
  float4 atv = *(const float4*)(att + c0);
  float at[4] = {atv.x, atv.y, atv.z, atv.w};
  float xrv[4];
  {
    union { short4 s; bf162 h[2]; } u;
    u.s = *(const short4*)(xlr + (size_t)v * 512 + 256 + c0);
    xrv[0] = __bfloat162float(u.h[0].x); xrv[1] = __bfloat162float(u.h[0].y);
    xrv[2] = __bfloat162float(u.h[1].x); xrv[3] = __bfloat162float(u.h[1].y);
  }

  const int beg = offs[v], end = offs[v + 1];
  const int len = end - beg;
  const int chunk = (len + 3) >> 2;
  int ib = beg + wave * chunk;
  int ie = ib + chunk;
  if (ib > end) ib = end;
  if (ie > end) ie = end;

  float den = 0.f, acc[4] = {0.f, 0.f, 0.f, 0.f};

  auto edge = [&](short4 qs, float4 e) {
    union { short4 s; bf162 h[2]; } u; u.s = qs;
    float xa[4] = {__bfloat162float(u.h[0].x), __bfloat162float(u.h[0].y),
                   __bfloat162float(u.h[1].x), __bfloat162float(u.h[1].y)};
    float p = 0.f;
#pragma unroll
    for (int j = 0; j < 4; j++) {
      float m = xa[j] + xrv[j];
      m = fmaf(e.x, w[0][j], m); m = fmaf(e.y, w[1][j], m);
      m = fmaf(e.z, w[2][j], m); m = fmaf(e.w, w[3][j], m);
      p = fmaf(fmaxf(m, 0.2f * m), at[j], p);
    }
#pragma unroll
    for (int o = 1; o < 64; o <<= 1) p += __shfl_xor(p, o);
    float ex = __expf(p);
    den += ex;
#pragma unroll
    for (int j = 0; j < 4; j++) acc[j] = fmaf(ex, xa[j], acc[j]);
  };

  int i = ib;
  for (; i + 4 <= ie; i += 4) {
    int s0 = srcs[i], s1 = srcs[i + 1], s2 = srcs[i + 2], s3 = srcs[i + 3];
    float4 e0 = eaC[i], e1 = eaC[i + 1], e2 = eaC[i + 2], e3 = eaC[i + 3];
    short4 q0 = *(const short4*)(xlr + (size_t)s0 * 512 + c0);
    short4 q1 = *(const short4*)(xlr + (size_t)s1 * 512 + c0);
    short4 q2 = *(const short4*)(xlr + (size_t)s2 * 512 + c0);
    short4 q3 = *(const short4*)(xlr + (size_t)s3 * 512 + c0);
    edge(q0, e0); edge(q1, e1); edge(q2, e2); edge(q3, e3);
  }
  for (; i < ie; ++i) {
    int s0 = srcs[i];
    float4 e0 = eaC[i];
    short4 q0 = *(const short4*)(xlr + (size_t)s0 * 512 + c0);
    edge(q0, e0);
  }

  // ----- cross-wave combine -----
  __shared__ float accs[4][HC2];
  __shared__ float dens[4];
  __shared__ float2 red[4];
  *(float4*)&accs[wave][c0] = *(float4*)&acc[0];
  if (lane == 0) dens[wave] = den;
  __syncthreads();

  const int c = tid;              // each thread: 1 channel
  const float dtot = dens[0] + dens[1] + dens[2] + dens[3];
  const float rden = 1.f / (dtot + 1e-16f);
  float val = (accs[0][c] + accs[1][c] + accs[2][c] + accs[3][c]) * rden + bias[c];

  float s1 = val, s2 = val * val;
#pragma unroll
  for (int o = 1; o < 64; o <<= 1) { s1 += __shfl_xor(s1, o); s2 += __shfl_xor(s2, o); }
  if (lane == 0) red[wave] = make_float2(s1, s2);
  __syncthreads();
  float ts1 = red[0].x + red[1].x + red[2].x + red[3].x;
  float ts2 = red[0].y + red[1].y + red[2].y + red[3].y;
  float mu  = ts1 * (1.f / HC2);
  float var = ts2 * (1.f / HC2) - mu * mu;
  float rs  = rsqrtf(var + 1e-5f);
  float y = (val - mu) * rs * g[c] + be[c];
  out[(size_t)v * HC2 + c] = y + xin[(size_t)v * HC2 + c];
}

// ---------------------------------------------------------------------------
extern "C" void kernel_launch(void* const* d_in, const int* in_sizes, int n_in,
                              void* d_out, int out_size, void* d_ws, size_t ws_size,
                              hipStream_t stream) {
  const float* x     = (const float*)d_in[0];
  const int*   ei    = (const int*)d_in[1];
  const float* eattr = (const float*)d_in[2];
  const float* Wl1   = (const float*)d_in[3];
  const float* Wr1   = (const float*)d_in[4];
  const float* We1   = (const float*)d_in[5];
  const float* att1  = (const float*)d_in[6];
  const float* b1    = (const float*)d_in[7];
  const float* g1    = (const float*)d_in[8];
  const float* be1   = (const float*)d_in[9];
  const float* Wl2   = (const float*)d_in[10];
  const float* Wr2   = (const float*)d_in[11];
  const float* We2   = (const float*)d_in[12];
  const float* att2  = (const float*)d_in[13];
  const float* b2    = (const float*)d_in[14];
  const float* g2    = (const float*)d_in[15];
  const float* be2   = (const float*)d_in[16];

  const int N    = in_sizes[0] / D_IN;   // 10000
  const int E    = in_sizes[2] / 4;      // 320000
  const int Etot = E + N;

  char* w = (char*)d_ws;
  auto alloc = [&](size_t bytes) -> void* {
    void* p = (void*)w;
    w += (bytes + 255) & ~(size_t)255;
    return p;
  };
  bf16*   xb    = (bf16*)alloc((size_t)N * D_IN * 2);
  bf16*   W1T   = (bf16*)alloc((size_t)1024 * 256 * 2);
  bf16*   W2T   = (bf16*)alloc((size_t)512 * 512 * 2);
  bf16*   xlr1  = (bf16*)alloc((size_t)N * 1024 * 2);
  bf16*   h1    = (bf16*)alloc((size_t)N * HC1 * 2);
  bf16*   xlr2  = (bf16*)alloc((size_t)N * 512 * 2);
  int*    srcs  = (int*)alloc((size_t)Etot * 4);
  float4* eaC   = (float4*)alloc((size_t)Etot * 16);
  int*    offs  = (int*)alloc((size_t)(N + 1) * 4);
  float*  mean4 = (float*)alloc(64);
  char*   zb    = w;
  int*    counts = (int*)alloc((size_t)N * 4);
  int*    cursor = (int*)alloc((size_t)N * 4);
  float*  sums   = (float*)alloc(64);
  size_t  zbytes = (size_t)(w - zb);

  hipMemsetAsync(zb, 0, zbytes, stream);

  int n4 = N * D_IN / 4;
  convx_kernel<<<(n4 + 255) / 256, 256, 0, stream>>>(x, xb, n4);
  transw_kernel<<<dim3(16, 16, 4), 256, 0, stream>>>(Wl1, Wr1, Wl2, Wr2, W1T, W2T);

  mean_kernel<<<256, 256, 0, stream>>>(eattr, sums, E);
  meanw_kernel<<<1, 64, 0, stream>>>(sums, mean4, 1.f / (float)E);

  count_kernel<<<1024, 256, 0, stream>>>(ei, counts, E, Etot);
  scan_kernel<<<1, 1024, 0, stream>>>(counts, offs, N);
  fill_kernel<<<1024, 256, 0, stream>>>(ei, offs, cursor, eattr, mean4, srcs, eaC, E, Etot);

  dim3 gg1(1024 / 128, (N + 127) / 128);
  gemm_mfma_kernel<<<gg1, 256, 0, stream>>>(xb, W1T, xlr1, N, 256, 1024);

  fused1_kernel<<<N, 256, 0, stream>>>(srcs, eaC, offs, xlr1, We1, att1, b1, g1, be1, h1);

  dim3 gg2(512 / 128, (N + 127) / 128);
  gemm_mfma_kernel<<<gg2, 256, 0, stream>>>(h1, W2T, xlr2, N, 512, 512);

  fused2_kernel<<<N, 256, 0, stream>>>(srcs, eaC, offs, xlr2, We2, att2,
                                       b2, g2, be2, x, (float*)d_out);
}